// Round 18
// baseline (257.001 us; speedup 1.0000x reference)
//
#include <hip/hip_runtime.h>
#include <hip/hip_bf16.h>

#define NN 16384
#define NC 64
#define GH 128
#define GW 128
#define GM 256

typedef __attribute__((ext_vector_type(8))) short bf16x8;
typedef __attribute__((ext_vector_type(4))) float f32x4;

static __device__ __forceinline__ int reflect128(int i){
  if (i < 0) i = -i;
  if (i > 127) i = 254 - i;
  return i;
}

// native RNE cast: compiler packs adjacent pairs into v_cvt_pk_bf16_f32
static __device__ __forceinline__ ushort f2bf(float f){
  __hip_bfloat16 h = __float2bfloat16(f);
  union { __hip_bfloat16 h; ushort u; } v; v.h = h;
  return v.u;
}

// px = round(0.5*(loc+1)*S - 0.5): bit-exact replica of reference f32 sequence
static __device__ __forceinline__ int cell_of(float l, float S2, int hi){
  l = fminf(fmaxf(l, -1.f), 1.f);
  float u = l + 1.f;
  int p = (int)rintf(u*S2 - 0.5f);
  return min(max(p,0),hi);
}

// grid-stride float4 zero
__global__ __launch_bounds__(256) void k_zero(float4* __restrict__ p, int n4){
  int i = blockIdx.x*256 + threadIdx.x;
  int stride = gridDim.x*256;
  float4 z = make_float4(0.f,0.f,0.f,0.f);
  for (; i < n4; i += stride) p[i] = z;
}

// scatter feat + (folded) cnt/csum/ccnt atomics on lanes c=0/1/2
__global__ __launch_bounds__(256) void k_scatter_feat2(
    const float* __restrict__ xsrc, const float* __restrict__ loc,
    const float* __restrict__ csrc, float* __restrict__ featg,
    float* __restrict__ cnt, float* __restrict__ csum, float* __restrict__ ccnt){
  int gid = blockIdx.x*256 + threadIdx.x;
  int t = gid >> 6, c = gid & 63;
  int b = t >> 14;
  int px = cell_of(loc[2*t],   64.f, 127);
  int py = cell_of(loc[2*t+1], 64.f, 127);
  int cell = (b*GH + py)*GW + px;
  atomicAdd(&featg[cell*NC + c], xsrc[gid]);
  if (c == 0){
    atomicAdd(&cnt[cell], 1.0f);
  } else if (c == 1){
    int qx = cell_of(loc[2*t],   8.f, 15);
    int qy = cell_of(loc[2*t+1], 8.f, 15);
    atomicAdd(&csum[b*GM + qy*16 + qx], csrc[t]);
  } else if (c == 2){
    int qx = cell_of(loc[2*t],   8.f, 15);
    int qy = cell_of(loc[2*t+1], 8.f, 15);
    atomicAdd(&ccnt[b*GM + qy*16 + qx], 1.0f);
  }
}

// fallback kernels (round-10 path) --------------------------------------
__global__ __launch_bounds__(256) void k_scatter_feat(
    const float* __restrict__ xsrc, const float* __restrict__ loc,
    float* __restrict__ featg){
  int gid = blockIdx.x*256 + threadIdx.x;
  int t = gid >> 6;
  int b = t >> 14;
  int px = cell_of(loc[2*t],   64.f, 127);
  int py = cell_of(loc[2*t+1], 64.f, 127);
  int cell = (b*GH + py)*GW + px;
  atomicAdd(&featg[cell*NC + (gid & 63)], xsrc[gid]);
}

__global__ __launch_bounds__(256) void k_scatter_aux(
    const float* __restrict__ loc, const float* __restrict__ csrc,
    float* __restrict__ cnt, float* __restrict__ csum, float* __restrict__ ccnt){
  int t = blockIdx.x*256 + threadIdx.x;
  int b = t >> 14;
  int px = cell_of(loc[2*t],   64.f, 127);
  int py = cell_of(loc[2*t+1], 64.f, 127);
  atomicAdd(&cnt[(b*GH+py)*GW+px], 1.0f);
  int qx = cell_of(loc[2*t],   8.f, 15);
  int qy = cell_of(loc[2*t+1], 8.f, 15);
  int cell = b*GM + qy*16 + qx;
  atomicAdd(&csum[cell], csrc[t]);
  atomicAdd(&ccnt[cell], 1.0f);
}

__global__ __launch_bounds__(256) void k_finalize_feat(
    float* __restrict__ featg, const float* __restrict__ cnt){
  int gid = blockIdx.x*256 + threadIdx.x;
  float cn = cnt[gid>>6];
  float v  = featg[gid];
  featg[gid] = (cn > 0.f) ? v/(cn+1e-6f) : 0.f;
}

__global__ __launch_bounds__(256) void k_finalize_conf(
    const float* __restrict__ csum, const float* __restrict__ ccnt,
    float* __restrict__ conf){
  int i = blockIdx.x*256 + threadIdx.x;
  float cn = ccnt[i];
  conf[i] = (cn > 0.f) ? csum[i]/(cn+1e-6f) : 0.f;
}

__global__ __launch_bounds__(256) void k_fill2(
    const float* __restrict__ cnt, float* __restrict__ feat){
  int gid = blockIdx.x*256 + threadIdx.x;
  int p = gid >> 2, cg = gid & 3;
  if (cnt[p] > 0.f) return;
  int b = p>>14, py=(p>>7)&127, px=p&127;
  const float fn = 0.039788735772973836f;
  float g1[9];
  #pragma unroll
  for (int i=0;i<9;++i){ float d=(float)i-4.f; g1[i]=__expf(-d*d*0.125f); }
  float4 acc[4];
  #pragma unroll
  for (int i=0;i<4;++i) acc[i]=make_float4(0.f,0.f,0.f,0.f);
  float msum=0.f;
  for (int dy=0; dy<9; ++dy){
    int iy = reflect128(py-4+dy);
    for (int dx=0; dx<9; ++dx){
      int ix = reflect128(px-4+dx);
      int q  = (b*GH+iy)*GW+ix;
      if (cnt[q] <= 0.f) continue;
      float wn = g1[dy]*g1[dx]*fn;
      msum += wn;
      const float4* fr = (const float4*)&feat[q*NC + cg*16];
      #pragma unroll
      for (int k=0;k<4;++k){
        float4 vv = fr[k];
        acc[k].x += wn*vv.x; acc[k].y += wn*vv.y;
        acc[k].z += wn*vv.z; acc[k].w += wn*vv.w;
      }
    }
  }
  if (msum <= 0.f) return;
  float inv = 1.f/(msum + 1e-6f);
  float4* o = (float4*)&feat[p*NC + cg*16];
  #pragma unroll
  for (int k=0;k<4;++k)
    o[k] = make_float4(acc[k].x*inv, acc[k].y*inv, acc[k].z*inv, acc[k].w*inv);
}

// ---------- separable fill, 8-batch, XCD-swizzled (T1) ----------
static __device__ __forceinline__ int rowswz(int bid){
  return ((bid & 7) << 7) + (bid >> 3);
}

__global__ __launch_bounds__(256) void k_finfillh(
    float* __restrict__ feat, const float* __restrict__ cnt,
    float* __restrict__ feath, float* __restrict__ maskh){
  __shared__ float F[GW*NC];                 // finalized row, 32 KB
  __shared__ float CR[GW];
  int py = rowswz(blockIdx.x), t = threadIdx.x;
  const float fn = 0.039788735772973836f;    // 1/(2*pi*var), var=4
  float g1n[9];
  #pragma unroll
  for (int i=0;i<9;++i){ float d=(float)i-4.f; g1n[i]=__expf(-d*d*0.125f)*fn; }
  if (t < GW) CR[t] = cnt[py*GW + t];
  __syncthreads();
  for (int i=t*4; i<GW*NC; i+=1024){
    int px = i>>6;
    float cn = CR[px];
    float inv = (cn > 0.f) ? 1.f/(cn+1e-6f) : 0.f;
    float4 v = *(const float4*)&feat[(size_t)py*GW*NC + i];
    v.x*=inv; v.y*=inv; v.z*=inv; v.w*=inv;
    *(float4*)&F[i] = v;
    *(float4*)&feat[(size_t)py*GW*NC + i] = v;
  }
  __syncthreads();
  for (int i=t*4; i<GW*NC; i+=1024){
    int px = i>>6, c = i&63;
    float4 acc = make_float4(0.f,0.f,0.f,0.f);
    #pragma unroll
    for (int dx=0; dx<9; ++dx){
      int ix = reflect128(px-4+dx);
      float w = g1n[dx];
      float4 v = *(const float4*)&F[ix*NC + c];
      acc.x += w*v.x; acc.y += w*v.y; acc.z += w*v.z; acc.w += w*v.w;
    }
    *(float4*)&feath[(size_t)py*GW*NC + i] = acc;
  }
  if (t < GW){
    float hm = 0.f;
    #pragma unroll
    for (int dx=0; dx<9; ++dx){
      int ix = reflect128(t-4+dx);
      hm += g1n[dx]*((CR[ix] > 0.f) ? 1.f : 0.f);
    }
    maskh[py*GW + t] = hm;
  }
}

__global__ __launch_bounds__(256) void k_fillv(
    float* __restrict__ feat, const float* __restrict__ cnt,
    const float* __restrict__ feath, const float* __restrict__ maskh){
  int pyg = rowswz(blockIdx.x), t = threadIdx.x;
  int b = pyg >> 7, pyl = pyg & 127;
  int px = t>>1, c0 = (t&1)<<5;
  float g1[9];
  #pragma unroll
  for (int i=0;i<9;++i){ float d=(float)i-4.f; g1[i]=__expf(-d*d*0.125f); }
  float cn = cnt[pyg*GW + px];
  float ym = 0.f;
  int ry[9];
  #pragma unroll
  for (int dy=0; dy<9; ++dy){
    ry[dy] = b*GH + reflect128(pyl-4+dy);
    ym += g1[dy]*maskh[ry[dy]*GW + px];
  }
  if (cn > 0.f || ym <= 0.f) return;
  float inv = 1.f/(ym + 1e-6f);
  float4 acc[8];
  #pragma unroll
  for (int k=0;k<8;++k) acc[k]=make_float4(0.f,0.f,0.f,0.f);
  #pragma unroll
  for (int dy=0; dy<9; ++dy){
    float w = g1[dy];
    const float4* hf = (const float4*)&feath[((size_t)ry[dy]*GW+px)*NC + c0];
    #pragma unroll
    for (int k=0;k<8;++k){
      float4 v = hf[k];
      acc[k].x += w*v.x; acc[k].y += w*v.y; acc[k].z += w*v.z; acc[k].w += w*v.w;
    }
  }
  float4* o = (float4*)&feat[((size_t)pyg*GW+px)*NC + c0];
  #pragma unroll
  for (int k=0;k<8;++k)
    o[k] = make_float4(acc[k].x*inv, acc[k].y*inv, acc[k].z*inv, acc[k].w*inv);
}

// ---------- fallback srconv (atomic split-K, proven) ----------
__global__ __launch_bounds__(256) void k_srconv(
    const float* __restrict__ feat, const float* __restrict__ srw,
    float* __restrict__ xs0){
  alignas(16) __shared__ float A[64*65];
  alignas(16) __shared__ float Bs[64*64];
  int mt = blockIdx.x, kh = blockIdx.y;
  int t = threadIdx.x;
  int tm = t>>4, tn = t&15;
  float acc[4][4] = {{0.f}};
  for (int kc=0; kc<8; ++kc){
    __syncthreads();
    for (int idx=t; idx<4096; idx+=256){
      int mr = idx>>6, kk = idx&63;
      int m = mt*64+mr;
      int b = m>>8, oh=(m>>4)&15, ow=m&15;
      A[mr*65+kk] = feat[(((b*GH)+(oh*8+kh))*GW + ow*8)*NC + kc*64 + kk];
    }
    for (int idx=t; idx<4096; idx+=256)
      Bs[idx] = srw[(kh*512 + kc*64)*64 + idx];
    __syncthreads();
    for (int kk=0; kk<64; ++kk){
      float4 bv = *(const float4*)&Bs[kk*64 + tn*4];
      #pragma unroll
      for (int i=0;i<4;++i){
        float av = A[(tm*4+i)*65 + kk];
        acc[i][0] += av*bv.x; acc[i][1] += av*bv.y;
        acc[i][2] += av*bv.z; acc[i][3] += av*bv.w;
      }
    }
  }
  #pragma unroll
  for (int i=0;i<4;++i)
    #pragma unroll
    for (int j=0;j<4;++j)
      atomicAdd(&xs0[(mt*64+tm*4+i)*64 + tn*4+j], acc[i][j]);
}

// ---------- srconv2: no atomics, 512 blocks, partials ----------
__global__ __launch_bounds__(256) void k_srconv2(
    const float* __restrict__ feat, const float* __restrict__ srw,
    float* __restrict__ part){
  alignas(16) __shared__ float A[64*65];
  alignas(16) __shared__ float Bs[64*64];
  int mt = blockIdx.x, kh = blockIdx.y, kq = blockIdx.z;
  int t = threadIdx.x;
  int tm = t>>4, tn = t&15;
  float acc[4][4] = {{0.f}};
  for (int kc=0; kc<4; ++kc){
    int kw = kq*4 + kc;
    __syncthreads();
    for (int idx=t; idx<4096; idx+=256){
      int mr = idx>>6, kk = idx&63;
      int m = mt*64+mr;
      int b = m>>8, oh=(m>>4)&15, ow=m&15;
      A[mr*65+kk] = feat[(((b*GH)+(oh*8+kh))*GW + ow*8 + kw)*NC + kk];
    }
    for (int idx=t; idx<4096; idx+=256)
      Bs[idx] = srw[(kh*512 + kw*64)*64 + idx];
    __syncthreads();
    for (int kk=0; kk<64; ++kk){
      float4 bv = *(const float4*)&Bs[kk*64 + tn*4];
      #pragma unroll
      for (int i=0;i<4;++i){
        float av = A[(tm*4+i)*65 + kk];
        acc[i][0] += av*bv.x; acc[i][1] += av*bv.y;
        acc[i][2] += av*bv.z; acc[i][3] += av*bv.w;
      }
    }
  }
  float* pdst = part + (size_t)(kh*2+kq)*2048*64;
  #pragma unroll
  for (int i=0;i<4;++i)
    #pragma unroll
    for (int j=0;j<4;++j)
      pdst[(mt*64+tm*4+i)*64 + tn*4+j] = acc[i][j];
}

// fallback layernorm (reads xs0)
__global__ __launch_bounds__(256) void k_ln(
    const float* __restrict__ xs0, const float* __restrict__ srb,
    const float* __restrict__ nw, const float* __restrict__ nbv,
    float* __restrict__ xs){
  int row  = blockIdx.x*4 + (threadIdx.x>>6);
  int lane = threadIdx.x & 63;
  float v = xs0[row*64+lane] + srb[lane];
  float s = v;
  #pragma unroll
  for (int off=32; off; off>>=1) s += __shfl_xor(s, off, 64);
  float mean = s*(1.f/64.f);
  float d = v - mean;
  float s2 = d*d;
  #pragma unroll
  for (int off=32; off; off>>=1) s2 += __shfl_xor(s2, off, 64);
  float var = s2*(1.f/64.f);
  xs[row*64+lane] = d*(1.f/sqrtf(var+1e-5f))*nw[lane] + nbv[lane];
}

// fallback kv kernels
__global__ __launch_bounds__(256) void k_kv1(
    const float* __restrict__ xs, const float* __restrict__ kvw,
    float* __restrict__ kraw, float* __restrict__ vraw){
  int gid = blockIdx.x*256 + threadIdx.x;
  int r = gid >> 6, d = gid & 63;
  const float* xr = &xs[r*64];
  float ka=0.f, va=0.f;
  for (int c=0;c<64;++c){
    float xc = xr[c];
    ka += xc*kvw[d*64+c];
    va += xc*kvw[(64+d)*64+c];
  }
  kraw[gid] = ka;
  vraw[gid] = va;
}

__global__ __launch_bounds__(256) void k_kvproj2(
    const float* __restrict__ kraw, const float* __restrict__ vraw,
    const float* __restrict__ qw, const float* __restrict__ pw,
    ushort* __restrict__ KB, ushort* __restrict__ VB){
  int gid = blockIdx.x*256 + threadIdx.x;
  int r = gid >> 6, c = gid & 63;
  int b = r >> 8, m = r & 255;
  const float* kr = &kraw[r*64];
  const float* vr = &vraw[r*64];
  float ak=0.f, av=0.f;
  for (int i=0;i<64;++i){
    ak += kr[i]*qw[i*64+c];
    av += vr[i]*pw[c*64+i];
  }
  {
    int nt = m>>4, l15 = m&15, kb = c>>5, h = (c>>3)&3, j = c&7;
    KB[((((b*16 + nt)*2 + kb)*4 + h)*16 + l15)*8 + j] = f2bf(ak);
  }
  {
    int ct = c>>4, n15 = c&15, kb2 = m>>5, h2 = (m>>3)&3, j2 = m&7;
    VB[((((b*4 + ct)*8 + kb2)*4 + h2)*16 + n15)*8 + j2] = f2bf(av);
  }
}

// ---- fused LN + kv + proj-fold + pack + (folded) conf finalize ----
__global__ __launch_bounds__(256) void k_kvfused2(
    const float* __restrict__ part, const float* __restrict__ srb,
    const float* __restrict__ nw, const float* __restrict__ nbv,
    const float* __restrict__ kvw, const float* __restrict__ qw,
    const float* __restrict__ pw,
    const float* __restrict__ csum, const float* __restrict__ ccnt,
    float* __restrict__ conf,
    ushort* __restrict__ KB, ushort* __restrict__ VB){
  __shared__ float XR[4][64], KR[4][64], VR[4][64];
  int t = threadIdx.x;
  int rl = t>>6, d = t&63;
  int r  = blockIdx.x*4 + rl;                // r = b*256+m == conf cell
  if (d == 0){
    float cn = ccnt[r];
    conf[r] = (cn > 0.f) ? csum[r]/(cn+1e-6f) : 0.f;
  }
  float v = srb[d];
  #pragma unroll
  for (int ps=0; ps<16; ++ps)
    v += part[(size_t)ps*2048*64 + r*64 + d];
  float s = v;
  #pragma unroll
  for (int off=32; off; off>>=1) s += __shfl_xor(s, off, 64);
  float mean = s*(1.f/64.f);
  float dd = v - mean;
  float s2 = dd*dd;
  #pragma unroll
  for (int off=32; off; off>>=1) s2 += __shfl_xor(s2, off, 64);
  float var = s2*(1.f/64.f);
  XR[rl][d] = dd*(1.f/sqrtf(var+1e-5f))*nw[d] + nbv[d];
  __syncthreads();
  float ka=0.f, va=0.f;
  for (int cc=0; cc<64; ++cc){
    float xc = XR[rl][cc];
    ka += xc*kvw[d*64+cc];
    va += xc*kvw[(64+d)*64+cc];
  }
  KR[rl][d] = ka; VR[rl][d] = va;
  __syncthreads();
  int c = d;
  float ak=0.f, av=0.f;
  for (int i=0;i<64;++i){
    ak += KR[rl][i]*qw[i*64+c];
    av += VR[rl][i]*pw[c*64+i];
  }
  int b = r>>8, m = r&255;
  {
    int nt = m>>4, l15 = m&15, kb = c>>5, h = (c>>3)&3, j = c&7;
    KB[((((b*16 + nt)*2 + kb)*4 + h)*16 + l15)*8 + j] = f2bf(ak);
  }
  {
    int ct = c>>4, n15 = c&15, kb2 = m>>5, h2 = (m>>3)&3, j2 = m&7;
    VB[((((b*4 + ct)*8 + kb2)*4 + h2)*16 + n15)*8 + j2] = f2bf(av);
  }
}

// fallback kvfused (no conf fold) for fallback path compat
__global__ __launch_bounds__(256) void k_kvfused(
    const float* __restrict__ part, const float* __restrict__ srb,
    const float* __restrict__ nw, const float* __restrict__ nbv,
    const float* __restrict__ kvw, const float* __restrict__ qw,
    const float* __restrict__ pw,
    ushort* __restrict__ KB, ushort* __restrict__ VB){
  __shared__ float XR[4][64], KR[4][64], VR[4][64];
  int t = threadIdx.x;
  int rl = t>>6, d = t&63;
  int r  = blockIdx.x*4 + rl;
  float v = srb[d];
  #pragma unroll
  for (int ps=0; ps<16; ++ps)
    v += part[(size_t)ps*2048*64 + r*64 + d];
  float s = v;
  #pragma unroll
  for (int off=32; off; off>>=1) s += __shfl_xor(s, off, 64);
  float mean = s*(1.f/64.f);
  float dd = v - mean;
  float s2 = dd*dd;
  #pragma unroll
  for (int off=32; off; off>>=1) s2 += __shfl_xor(s2, off, 64);
  float var = s2*(1.f/64.f);
  XR[rl][d] = dd*(1.f/sqrtf(var+1e-5f))*nw[d] + nbv[d];
  __syncthreads();
  float ka=0.f, va=0.f;
  for (int cc=0; cc<64; ++cc){
    float xc = XR[rl][cc];
    ka += xc*kvw[d*64+cc];
    va += xc*kvw[(64+d)*64+cc];
  }
  KR[rl][d] = ka; VR[rl][d] = va;
  __syncthreads();
  int c = d;
  float ak=0.f, av=0.f;
  for (int i=0;i<64;++i){
    ak += KR[rl][i]*qw[i*64+c];
    av += VR[rl][i]*pw[c*64+i];
  }
  int b = r>>8, m = r&255;
  {
    int nt = m>>4, l15 = m&15, kb = c>>5, h = (c>>3)&3, j = c&7;
    KB[((((b*16 + nt)*2 + kb)*4 + h)*16 + l15)*8 + j] = f2bf(ak);
  }
  {
    int ct = c>>4, n15 = c&15, kb2 = m>>5, h2 = (m>>3)&3, j2 = m&7;
    VB[((((b*4 + ct)*8 + kb2)*4 + h2)*16 + n15)*8 + j2] = f2bf(av);
  }
}

// fallback MFMA attention (monolithic, proven)
__global__ __launch_bounds__(256) void k_attn5(
    const float* __restrict__ x, const ushort* __restrict__ KB,
    const ushort* __restrict__ VB, const float* __restrict__ conf,
    const float* __restrict__ projb, float* __restrict__ out){
  alignas(16) __shared__ ushort P[4*4096];
  int t = threadIdx.x, w = t>>6, l = t&63;
  int b = blockIdx.x >> 8;
  int row0 = ((blockIdx.x & 255) << 6) + (w<<4);
  int l15 = l & 15, h = l >> 4;
  const ushort* KBb = KB + b*16384;
  const ushort* VBb = VB + b*16384;
  bf16x8 xa[2];
  {
    const float* xr = x + (size_t)(b*NN + row0 + l15)*64 + h*8;
    #pragma unroll
    for (int kb=0; kb<2; ++kb){
      float4 a0 = *(const float4*)(xr + 32*kb);
      float4 a1 = *(const float4*)(xr + 32*kb + 4);
      bf16x8 v;
      v[0]=(short)f2bf(a0.x); v[1]=(short)f2bf(a0.y);
      v[2]=(short)f2bf(a0.z); v[3]=(short)f2bf(a0.w);
      v[4]=(short)f2bf(a1.x); v[5]=(short)f2bf(a1.y);
      v[6]=(short)f2bf(a1.z); v[7]=(short)f2bf(a1.w);
      xa[kb]=v;
    }
  }
  f32x4 acc[16];
  #pragma unroll
  for (int nt=0;nt<16;++nt) acc[nt] = (f32x4){0.f,0.f,0.f,0.f};
  #pragma unroll
  for (int nt=0;nt<16;++nt){
    bf16x8 b0 = *(const bf16x8*)(KBb + (nt*2+0)*512 + l*8);
    bf16x8 b1 = *(const bf16x8*)(KBb + (nt*2+1)*512 + l*8);
    acc[nt] = __builtin_amdgcn_mfma_f32_16x16x32_bf16(xa[0], b0, acc[nt], 0,0,0);
    acc[nt] = __builtin_amdgcn_mfma_f32_16x16x32_bf16(xa[1], b1, acc[nt], 0,0,0);
  }
  float rs[4] = {0.f,0.f,0.f,0.f};
  ushort* Pw = P + w*4096;
  #pragma unroll
  for (int nt=0;nt<16;++nt){
    float cf = conf[b*GM + nt*16 + l15];
    #pragma unroll
    for (int reg=0;reg<4;++reg){
      float p = __expf(fmaf(acc[nt][reg], 0.125f, cf));
      rs[reg] += p;
      int m   = nt*16 + l15;
      int row = h*4 + reg;
      int ld  = ((m>>3)&3)*16 + row;
      int idx = ((m>>5)*512 + ld*8 + (m&7)) ^ (ld & 0x38);
      Pw[idx] = f2bf(p);
    }
  }
  #pragma unroll
  for (int off=1; off<16; off<<=1){
    #pragma unroll
    for (int reg=0;reg<4;++reg) rs[reg] += __shfl_xor(rs[reg], off, 64);
  }
  f32x4 oacc[4];
  #pragma unroll
  for (int ct=0;ct<4;++ct) oacc[ct] = (f32x4){0.f,0.f,0.f,0.f};
  #pragma unroll
  for (int kb2=0;kb2<8;++kb2){
    int ridx = (kb2*512 + l*8) ^ (l & 0x38);
    bf16x8 pa = *(const bf16x8*)(Pw + ridx);
    #pragma unroll
    for (int ct=0;ct<4;++ct){
      bf16x8 vb = *(const bf16x8*)(VBb + (ct*8+kb2)*512 + l*8);
      oacc[ct] = __builtin_amdgcn_mfma_f32_16x16x32_bf16(pa, vb, oacc[ct], 0,0,0);
    }
  }
  float* OT = (float*)Pw;
  #pragma unroll
  for (int ct=0;ct<4;++ct){
    float pb4 = projb[ct*16 + l15];
    #pragma unroll
    for (int reg=0;reg<4;++reg)
      OT[(h*4+reg)*68 + ct*16 + l15] = oacc[ct][reg]/rs[reg] + pb4;
  }
  #pragma unroll
  for (int i=0;i<4;++i){
    int row = i*4 + h;
    float4 v = *(const float4*)&OT[row*68 + l15*4];
    *(float4*)&out[(size_t)(b*NN + row0 + row)*64 + l15*4] = v;
  }
}

// ---------- attn8: attn6 re-partitioned to 1-wave blocks ----------
// attn6 (proven 39.8us) was occupancy-quantized at 2x4-wave blocks; same code
// with 64-thread blocks + 8KB LDS lets ~16 blocks/CU reside (LDS-capped).
__global__ __launch_bounds__(64) void k_attn8(
    const float* __restrict__ x, const ushort* __restrict__ KB,
    const ushort* __restrict__ VB, const float* __restrict__ conf,
    const float* __restrict__ projb, float* __restrict__ out){
  alignas(16) __shared__ ushort Pw[4096];      // 8 KB, wave-private
  int l = threadIdx.x;
  int b = blockIdx.x >> 10;
  int row0 = (blockIdx.x & 1023) << 4;
  int l15 = l & 15, h = l >> 4;
  const ushort* KBb = KB + b*16384;
  const ushort* VBb = VB + b*16384;

  bf16x8 xa[2];
  {
    const float* xr = x + (size_t)(b*NN + row0 + l15)*64 + h*8;
    #pragma unroll
    for (int kb=0; kb<2; ++kb){
      float4 a0 = *(const float4*)(xr + 32*kb);
      float4 a1 = *(const float4*)(xr + 32*kb + 4);
      bf16x8 v;
      v[0]=(short)f2bf(a0.x); v[1]=(short)f2bf(a0.y);
      v[2]=(short)f2bf(a0.z); v[3]=(short)f2bf(a0.w);
      v[4]=(short)f2bf(a1.x); v[5]=(short)f2bf(a1.y);
      v[6]=(short)f2bf(a1.z); v[7]=(short)f2bf(a1.w);
      xa[kb]=v;
    }
  }

  float rs[4] = {0.f,0.f,0.f,0.f};
  f32x4 oacc[4];
  #pragma unroll
  for (int ct=0;ct<4;++ct) oacc[ct] = (f32x4){0.f,0.f,0.f,0.f};

  #pragma unroll
  for (int c=0;c<4;++c){
    f32x4 acc[4];
    #pragma unroll
    for (int q=0;q<4;++q) acc[q] = (f32x4){0.f,0.f,0.f,0.f};
    #pragma unroll
    for (int q=0;q<4;++q){
      int nt = c*4 + q;
      bf16x8 b0 = *(const bf16x8*)(KBb + (nt*2+0)*512 + l*8);
      bf16x8 b1 = *(const bf16x8*)(KBb + (nt*2+1)*512 + l*8);
      acc[q] = __builtin_amdgcn_mfma_f32_16x16x32_bf16(xa[0], b0, acc[q], 0,0,0);
      acc[q] = __builtin_amdgcn_mfma_f32_16x16x32_bf16(xa[1], b1, acc[q], 0,0,0);
    }
    #pragma unroll
    for (int q=0;q<4;++q){
      int nt = c*4 + q;
      float cf = conf[b*GM + nt*16 + l15];
      #pragma unroll
      for (int reg=0;reg<4;++reg){
        float p = __expf(fmaf(acc[q][reg], 0.125f, cf));
        rs[reg] += p;
        int m   = nt*16 + l15;
        int row = h*4 + reg;
        int ld  = ((m>>3)&3)*16 + row;
        int idx = ((m>>5)*512 + ld*8 + (m&7)) ^ (ld & 0x38);
        Pw[idx] = f2bf(p);
      }
    }
    #pragma unroll
    for (int kk=0;kk<2;++kk){
      int kb2 = c*2 + kk;
      int ridx = (kb2*512 + l*8) ^ (l & 0x38);
      bf16x8 pa = *(const bf16x8*)(Pw + ridx);
      #pragma unroll
      for (int ct=0;ct<4;++ct){
        bf16x8 vb = *(const bf16x8*)(VBb + (ct*8+kb2)*512 + l*8);
        oacc[ct] = __builtin_amdgcn_mfma_f32_16x16x32_bf16(pa, vb, oacc[ct], 0,0,0);
      }
    }
  }

  #pragma unroll
  for (int off=1; off<16; off<<=1){
    #pragma unroll
    for (int reg=0;reg<4;++reg) rs[reg] += __shfl_xor(rs[reg], off, 64);
  }

  float* OT = (float*)Pw;
  #pragma unroll
  for (int ct=0;ct<4;++ct){
    float pb4 = projb[ct*16 + l15];
    #pragma unroll
    for (int reg=0;reg<4;++reg)
      OT[(h*4+reg)*68 + ct*16 + l15] = oacc[ct][reg]/rs[reg] + pb4;
  }
  #pragma unroll
  for (int i=0;i<4;++i){
    int row = i*4 + h;
    float4 v = *(const float4*)&OT[row*68 + l15*4];
    *(float4*)&out[(size_t)(b*NN + row0 + row)*64 + l15*4] = v;
  }
}

extern "C" void kernel_launch(void* const* d_in, const int* in_sizes, int n_in,
                              void* d_out, int out_size, void* d_ws, size_t ws_size,
                              hipStream_t stream){
  const float* x    = (const float*)d_in[0];
  const float* xsrc = (const float*)d_in[1];
  const float* loc  = (const float*)d_in[2];
  const float* csrc = (const float*)d_in[3];
  const float* qw   = (const float*)d_in[4];
  const float* kvw  = (const float*)d_in[5];
  const float* srw  = (const float*)d_in[6];
  const float* srb  = (const float*)d_in[7];
  const float* nw   = (const float*)d_in[8];
  const float* nbv  = (const float*)d_in[9];
  const float* pw   = (const float*)d_in[10];
  const float* pb   = (const float*)d_in[11];
  float* out = (float*)d_out;
  float* ws = (float*)d_ws;

  // ===== primary layout (all 8-batch, separable fill, conv partials) =====
  size_t of_feat  = 0;
  size_t of_cnt   = of_feat  + 8ull*GH*GW*NC;
  size_t of_csum  = of_cnt   + 8ull*GH*GW;
  size_t of_ccnt  = of_csum  + 8ull*GM;
  size_t zero_end = of_ccnt  + 8ull*GM;
  size_t of_feath = zero_end;
  size_t of_maskh = of_feath + 8ull*GH*GW*NC;
  size_t of_part  = of_maskh + 8ull*GH*GW;
  size_t of_conf  = of_part  + 16ull*2048*64;
  size_t of_kb    = of_conf  + 8ull*GM;
  size_t of_vb    = of_kb    + 8ull*8192;
  size_t total_p  = of_vb    + 8ull*8192;

  if (ws_size >= total_p*sizeof(float)){
    k_zero          <<<2048,        256, 0, stream>>>((float4*)ws, (int)(zero_end>>2));
    k_scatter_feat2 <<<8*NN*NC/256, 256, 0, stream>>>(xsrc, loc, csrc, ws+of_feat,
                                                      ws+of_cnt, ws+of_csum, ws+of_ccnt);
    k_finfillh      <<<8*GH,        256, 0, stream>>>(ws+of_feat, ws+of_cnt, ws+of_feath, ws+of_maskh);
    k_fillv         <<<8*GH,        256, 0, stream>>>(ws+of_feat, ws+of_cnt, ws+of_feath, ws+of_maskh);
    dim3 gconv(32, 8, 2);
    k_srconv2       <<<gconv,       256, 0, stream>>>(ws+of_feat, srw, ws+of_part);
    k_kvfused2      <<<8*GM/4,      256, 0, stream>>>(ws+of_part, srb, nw, nbv, kvw, qw, pw,
                                                      ws+of_csum, ws+of_ccnt, ws+of_conf,
                                                      (ushort*)(ws+of_kb), (ushort*)(ws+of_vb));
    k_attn8         <<<8*NN/16,     64,  0, stream>>>(x, (const ushort*)(ws+of_kb),
                                                      (const ushort*)(ws+of_vb),
                                                      ws+of_conf, pb, out);
  } else {
    // ---------------- fallback: exact round-10 8-batch path ----------------
    size_t f_feat = 0;
    size_t f_cnt  = f_feat + 8ull*GH*GW*NC;
    size_t f_csum = f_cnt  + 8ull*GH*GW;
    size_t f_ccnt = f_csum + 8ull*GM;
    size_t f_xs0  = f_ccnt + 8ull*GM;
    size_t f_zero = f_xs0  + 8ull*GM*NC;
    size_t f_conf = f_zero;
    size_t f_xs   = f_conf + 8ull*GM;
    size_t f_kr   = f_xs   + 8ull*GM*NC;
    size_t f_vr   = f_kr   + 8ull*GM*NC;
    size_t f_kb   = f_vr   + 8ull*GM*NC;
    size_t f_vb   = f_kb   + 8ull*8192;
    hipMemsetAsync(ws, 0, f_zero*sizeof(float), stream);
    k_scatter_feat <<<8*NN*NC/256, 256, 0, stream>>>(xsrc, loc, ws+f_feat);
    k_scatter_aux  <<<8*NN/256,    256, 0, stream>>>(loc, csrc, ws+f_cnt, ws+f_csum, ws+f_ccnt);
    k_finalize_feat<<<8*GH*GW*NC/256, 256, 0, stream>>>(ws+f_feat, ws+f_cnt);
    k_finalize_conf<<<8*GM/256,    256, 0, stream>>>(ws+f_csum, ws+f_ccnt, ws+f_conf);
    k_fill2        <<<8*GH*GW*4/256, 256, 0, stream>>>(ws+f_cnt, ws+f_feat);
    dim3 gconv(8*GM/64, 8);
    k_srconv       <<<gconv,       256, 0, stream>>>(ws+f_feat, srw, ws+f_xs0);
    k_ln           <<<8*GM/4,      256, 0, stream>>>(ws+f_xs0, srb, nw, nbv, ws+f_xs);
    k_kv1          <<<8*GM*NC/256, 256, 0, stream>>>(ws+f_xs, kvw, ws+f_kr, ws+f_vr);
    k_kvproj2      <<<8*GM*NC/256, 256, 0, stream>>>(ws+f_kr, ws+f_vr, qw, pw,
                                                     (ushort*)(ws+f_kb), (ushort*)(ws+f_vb));
    k_attn5        <<<8*NN/64,     256, 0, stream>>>(x, (const ushort*)(ws+f_kb),
                                                     (const ushort*)(ws+f_vb),
                                                     ws+f_conf, pb, out);
  }
}

// Round 19
// 181.180 us; speedup vs baseline: 1.4185x; 1.4185x over previous
//
#include <hip/hip_runtime.h>
#include <hip/hip_bf16.h>

#define NN 16384
#define NC 64
#define GH 128
#define GW 128
#define GM 256

typedef __attribute__((ext_vector_type(8))) short bf16x8;
typedef __attribute__((ext_vector_type(4))) float f32x4;

static __device__ __forceinline__ int reflect128(int i){
  if (i < 0) i = -i;
  if (i > 127) i = 254 - i;
  return i;
}

// native RNE cast: compiler packs adjacent pairs into v_cvt_pk_bf16_f32
static __device__ __forceinline__ ushort f2bf(float f){
  __hip_bfloat16 h = __float2bfloat16(f);
  union { __hip_bfloat16 h; ushort u; } v; v.h = h;
  return v.u;
}

// px = round(0.5*(loc+1)*S - 0.5): bit-exact replica of reference f32 sequence
static __device__ __forceinline__ int cell_of(float l, float S2, int hi){
  l = fminf(fmaxf(l, -1.f), 1.f);
  float u = l + 1.f;
  int p = (int)rintf(u*S2 - 0.5f);
  return min(max(p,0),hi);
}

// grid-stride float4 zero
__global__ __launch_bounds__(256) void k_zero(float4* __restrict__ p, int n4){
  int i = blockIdx.x*256 + threadIdx.x;
  int stride = gridDim.x*256;
  float4 z = make_float4(0.f,0.f,0.f,0.f);
  for (; i < n4; i += stride) p[i] = z;
}

// NOTE round-18 lesson: folding per-token atomics into the per-(token,chan)
// grid made them single-active-lane divergent atomics (64x instr count,
// 130us). Keep scatter split: full-wave atomics only.
__global__ __launch_bounds__(256) void k_scatter_feat(
    const float* __restrict__ xsrc, const float* __restrict__ loc,
    float* __restrict__ featg){
  int gid = blockIdx.x*256 + threadIdx.x;
  int t = gid >> 6;
  int b = t >> 14;
  int px = cell_of(loc[2*t],   64.f, 127);
  int py = cell_of(loc[2*t+1], 64.f, 127);
  int cell = (b*GH + py)*GW + px;
  atomicAdd(&featg[cell*NC + (gid & 63)], xsrc[gid]);
}

__global__ __launch_bounds__(256) void k_scatter_aux(
    const float* __restrict__ loc, const float* __restrict__ csrc,
    float* __restrict__ cnt, float* __restrict__ csum, float* __restrict__ ccnt){
  int t = blockIdx.x*256 + threadIdx.x;
  int b = t >> 14;
  int px = cell_of(loc[2*t],   64.f, 127);
  int py = cell_of(loc[2*t+1], 64.f, 127);
  atomicAdd(&cnt[(b*GH+py)*GW+px], 1.0f);
  int qx = cell_of(loc[2*t],   8.f, 15);
  int qy = cell_of(loc[2*t+1], 8.f, 15);
  int cell = b*GM + qy*16 + qx;
  atomicAdd(&csum[cell], csrc[t]);
  atomicAdd(&ccnt[cell], 1.0f);
}

__global__ __launch_bounds__(256) void k_finalize_feat(
    float* __restrict__ featg, const float* __restrict__ cnt){
  int gid = blockIdx.x*256 + threadIdx.x;
  float cn = cnt[gid>>6];
  float v  = featg[gid];
  featg[gid] = (cn > 0.f) ? v/(cn+1e-6f) : 0.f;
}

__global__ __launch_bounds__(256) void k_finalize_conf(
    const float* __restrict__ csum, const float* __restrict__ ccnt,
    float* __restrict__ conf){
  int i = blockIdx.x*256 + threadIdx.x;
  float cn = ccnt[i];
  conf[i] = (cn > 0.f) ? csum[i]/(cn+1e-6f) : 0.f;
}

// ---------- fallback fill (81-tap, 8-batch, proven) ----------
__global__ __launch_bounds__(256) void k_fill2(
    const float* __restrict__ cnt, float* __restrict__ feat){
  int gid = blockIdx.x*256 + threadIdx.x;
  int p = gid >> 2, cg = gid & 3;
  if (cnt[p] > 0.f) return;
  int b = p>>14, py=(p>>7)&127, px=p&127;
  const float fn = 0.039788735772973836f;
  float g1[9];
  #pragma unroll
  for (int i=0;i<9;++i){ float d=(float)i-4.f; g1[i]=__expf(-d*d*0.125f); }
  float4 acc[4];
  #pragma unroll
  for (int i=0;i<4;++i) acc[i]=make_float4(0.f,0.f,0.f,0.f);
  float msum=0.f;
  for (int dy=0; dy<9; ++dy){
    int iy = reflect128(py-4+dy);
    for (int dx=0; dx<9; ++dx){
      int ix = reflect128(px-4+dx);
      int q  = (b*GH+iy)*GW+ix;
      if (cnt[q] <= 0.f) continue;
      float wn = g1[dy]*g1[dx]*fn;
      msum += wn;
      const float4* fr = (const float4*)&feat[q*NC + cg*16];
      #pragma unroll
      for (int k=0;k<4;++k){
        float4 vv = fr[k];
        acc[k].x += wn*vv.x; acc[k].y += wn*vv.y;
        acc[k].z += wn*vv.z; acc[k].w += wn*vv.w;
      }
    }
  }
  if (msum <= 0.f) return;
  float inv = 1.f/(msum + 1e-6f);
  float4* o = (float4*)&feat[p*NC + cg*16];
  #pragma unroll
  for (int k=0;k<4;++k)
    o[k] = make_float4(acc[k].x*inv, acc[k].y*inv, acc[k].z*inv, acc[k].w*inv);
}

// ---------- separable fill, 8-batch, XCD-swizzled (T1) ----------
static __device__ __forceinline__ int rowswz(int bid){
  return ((bid & 7) << 7) + (bid >> 3);
}

__global__ __launch_bounds__(256) void k_finfillh(
    float* __restrict__ feat, const float* __restrict__ cnt,
    float* __restrict__ feath, float* __restrict__ maskh){
  __shared__ float F[GW*NC];                 // finalized row, 32 KB
  __shared__ float CR[GW];
  int py = rowswz(blockIdx.x), t = threadIdx.x;
  const float fn = 0.039788735772973836f;    // 1/(2*pi*var), var=4
  float g1n[9];
  #pragma unroll
  for (int i=0;i<9;++i){ float d=(float)i-4.f; g1n[i]=__expf(-d*d*0.125f)*fn; }
  if (t < GW) CR[t] = cnt[py*GW + t];
  __syncthreads();
  for (int i=t*4; i<GW*NC; i+=1024){
    int px = i>>6;
    float cn = CR[px];
    float inv = (cn > 0.f) ? 1.f/(cn+1e-6f) : 0.f;
    float4 v = *(const float4*)&feat[(size_t)py*GW*NC + i];
    v.x*=inv; v.y*=inv; v.z*=inv; v.w*=inv;
    *(float4*)&F[i] = v;
    *(float4*)&feat[(size_t)py*GW*NC + i] = v;
  }
  __syncthreads();
  for (int i=t*4; i<GW*NC; i+=1024){
    int px = i>>6, c = i&63;
    float4 acc = make_float4(0.f,0.f,0.f,0.f);
    #pragma unroll
    for (int dx=0; dx<9; ++dx){
      int ix = reflect128(px-4+dx);
      float w = g1n[dx];
      float4 v = *(const float4*)&F[ix*NC + c];
      acc.x += w*v.x; acc.y += w*v.y; acc.z += w*v.z; acc.w += w*v.w;
    }
    *(float4*)&feath[(size_t)py*GW*NC + i] = acc;
  }
  if (t < GW){
    float hm = 0.f;
    #pragma unroll
    for (int dx=0; dx<9; ++dx){
      int ix = reflect128(t-4+dx);
      hm += g1n[dx]*((CR[ix] > 0.f) ? 1.f : 0.f);
    }
    maskh[py*GW + t] = hm;
  }
}

__global__ __launch_bounds__(256) void k_fillv(
    float* __restrict__ feat, const float* __restrict__ cnt,
    const float* __restrict__ feath, const float* __restrict__ maskh){
  int pyg = rowswz(blockIdx.x), t = threadIdx.x;
  int b = pyg >> 7, pyl = pyg & 127;
  int px = t>>1, c0 = (t&1)<<5;
  float g1[9];
  #pragma unroll
  for (int i=0;i<9;++i){ float d=(float)i-4.f; g1[i]=__expf(-d*d*0.125f); }
  float cn = cnt[pyg*GW + px];
  float ym = 0.f;
  int ry[9];
  #pragma unroll
  for (int dy=0; dy<9; ++dy){
    ry[dy] = b*GH + reflect128(pyl-4+dy);
    ym += g1[dy]*maskh[ry[dy]*GW + px];
  }
  if (cn > 0.f || ym <= 0.f) return;
  float inv = 1.f/(ym + 1e-6f);
  float4 acc[8];
  #pragma unroll
  for (int k=0;k<8;++k) acc[k]=make_float4(0.f,0.f,0.f,0.f);
  #pragma unroll
  for (int dy=0; dy<9; ++dy){
    float w = g1[dy];
    const float4* hf = (const float4*)&feath[((size_t)ry[dy]*GW+px)*NC + c0];
    #pragma unroll
    for (int k=0;k<8;++k){
      float4 v = hf[k];
      acc[k].x += w*v.x; acc[k].y += w*v.y; acc[k].z += w*v.z; acc[k].w += w*v.w;
    }
  }
  float4* o = (float4*)&feat[((size_t)pyg*GW+px)*NC + c0];
  #pragma unroll
  for (int k=0;k<8;++k)
    o[k] = make_float4(acc[k].x*inv, acc[k].y*inv, acc[k].z*inv, acc[k].w*inv);
}

// ---------- fallback srconv (atomic split-K, proven) ----------
__global__ __launch_bounds__(256) void k_srconv(
    const float* __restrict__ feat, const float* __restrict__ srw,
    float* __restrict__ xs0){
  alignas(16) __shared__ float A[64*65];
  alignas(16) __shared__ float Bs[64*64];
  int mt = blockIdx.x, kh = blockIdx.y;
  int t = threadIdx.x;
  int tm = t>>4, tn = t&15;
  float acc[4][4] = {{0.f}};
  for (int kc=0; kc<8; ++kc){
    __syncthreads();
    for (int idx=t; idx<4096; idx+=256){
      int mr = idx>>6, kk = idx&63;
      int m = mt*64+mr;
      int b = m>>8, oh=(m>>4)&15, ow=m&15;
      A[mr*65+kk] = feat[(((b*GH)+(oh*8+kh))*GW + ow*8)*NC + kc*64 + kk];
    }
    for (int idx=t; idx<4096; idx+=256)
      Bs[idx] = srw[(kh*512 + kc*64)*64 + idx];
    __syncthreads();
    for (int kk=0; kk<64; ++kk){
      float4 bv = *(const float4*)&Bs[kk*64 + tn*4];
      #pragma unroll
      for (int i=0;i<4;++i){
        float av = A[(tm*4+i)*65 + kk];
        acc[i][0] += av*bv.x; acc[i][1] += av*bv.y;
        acc[i][2] += av*bv.z; acc[i][3] += av*bv.w;
      }
    }
  }
  #pragma unroll
  for (int i=0;i<4;++i)
    #pragma unroll
    for (int j=0;j<4;++j)
      atomicAdd(&xs0[(mt*64+tm*4+i)*64 + tn*4+j], acc[i][j]);
}

// ---------- srconv2: no atomics, 512 blocks, partials ----------
__global__ __launch_bounds__(256) void k_srconv2(
    const float* __restrict__ feat, const float* __restrict__ srw,
    float* __restrict__ part){
  alignas(16) __shared__ float A[64*65];
  alignas(16) __shared__ float Bs[64*64];
  int mt = blockIdx.x, kh = blockIdx.y, kq = blockIdx.z;
  int t = threadIdx.x;
  int tm = t>>4, tn = t&15;
  float acc[4][4] = {{0.f}};
  for (int kc=0; kc<4; ++kc){
    int kw = kq*4 + kc;
    __syncthreads();
    for (int idx=t; idx<4096; idx+=256){
      int mr = idx>>6, kk = idx&63;
      int m = mt*64+mr;
      int b = m>>8, oh=(m>>4)&15, ow=m&15;
      A[mr*65+kk] = feat[(((b*GH)+(oh*8+kh))*GW + ow*8 + kw)*NC + kk];
    }
    for (int idx=t; idx<4096; idx+=256)
      Bs[idx] = srw[(kh*512 + kw*64)*64 + idx];
    __syncthreads();
    for (int kk=0; kk<64; ++kk){
      float4 bv = *(const float4*)&Bs[kk*64 + tn*4];
      #pragma unroll
      for (int i=0;i<4;++i){
        float av = A[(tm*4+i)*65 + kk];
        acc[i][0] += av*bv.x; acc[i][1] += av*bv.y;
        acc[i][2] += av*bv.z; acc[i][3] += av*bv.w;
      }
    }
  }
  float* pdst = part + (size_t)(kh*2+kq)*2048*64;
  #pragma unroll
  for (int i=0;i<4;++i)
    #pragma unroll
    for (int j=0;j<4;++j)
      pdst[(mt*64+tm*4+i)*64 + tn*4+j] = acc[i][j];
}

// fallback layernorm (reads xs0)
__global__ __launch_bounds__(256) void k_ln(
    const float* __restrict__ xs0, const float* __restrict__ srb,
    const float* __restrict__ nw, const float* __restrict__ nbv,
    float* __restrict__ xs){
  int row  = blockIdx.x*4 + (threadIdx.x>>6);
  int lane = threadIdx.x & 63;
  float v = xs0[row*64+lane] + srb[lane];
  float s = v;
  #pragma unroll
  for (int off=32; off; off>>=1) s += __shfl_xor(s, off, 64);
  float mean = s*(1.f/64.f);
  float d = v - mean;
  float s2 = d*d;
  #pragma unroll
  for (int off=32; off; off>>=1) s2 += __shfl_xor(s2, off, 64);
  float var = s2*(1.f/64.f);
  xs[row*64+lane] = d*(1.f/sqrtf(var+1e-5f))*nw[lane] + nbv[lane];
}

// fallback kv kernels
__global__ __launch_bounds__(256) void k_kv1(
    const float* __restrict__ xs, const float* __restrict__ kvw,
    float* __restrict__ kraw, float* __restrict__ vraw){
  int gid = blockIdx.x*256 + threadIdx.x;
  int r = gid >> 6, d = gid & 63;
  const float* xr = &xs[r*64];
  float ka=0.f, va=0.f;
  for (int c=0;c<64;++c){
    float xc = xr[c];
    ka += xc*kvw[d*64+c];
    va += xc*kvw[(64+d)*64+c];
  }
  kraw[gid] = ka;
  vraw[gid] = va;
}

__global__ __launch_bounds__(256) void k_kvproj2(
    const float* __restrict__ kraw, const float* __restrict__ vraw,
    const float* __restrict__ qw, const float* __restrict__ pw,
    ushort* __restrict__ KB, ushort* __restrict__ VB){
  int gid = blockIdx.x*256 + threadIdx.x;
  int r = gid >> 6, c = gid & 63;
  int b = r >> 8, m = r & 255;
  const float* kr = &kraw[r*64];
  const float* vr = &vraw[r*64];
  float ak=0.f, av=0.f;
  for (int i=0;i<64;++i){
    ak += kr[i]*qw[i*64+c];
    av += vr[i]*pw[c*64+i];
  }
  {
    int nt = m>>4, l15 = m&15, kb = c>>5, h = (c>>3)&3, j = c&7;
    KB[((((b*16 + nt)*2 + kb)*4 + h)*16 + l15)*8 + j] = f2bf(ak);
  }
  {
    int ct = c>>4, n15 = c&15, kb2 = m>>5, h2 = (m>>3)&3, j2 = m&7;
    VB[((((b*4 + ct)*8 + kb2)*4 + h2)*16 + n15)*8 + j2] = f2bf(av);
  }
}

// ---- fused LN + kv + proj-fold + pack + (folded) conf finalize ----
// conf fold is grid-shape-matched (1 lane per conf cell) — safe, unlike the
// scatter fold (round-18 lesson).
__global__ __launch_bounds__(256) void k_kvfused2(
    const float* __restrict__ part, const float* __restrict__ srb,
    const float* __restrict__ nw, const float* __restrict__ nbv,
    const float* __restrict__ kvw, const float* __restrict__ qw,
    const float* __restrict__ pw,
    const float* __restrict__ csum, const float* __restrict__ ccnt,
    float* __restrict__ conf,
    ushort* __restrict__ KB, ushort* __restrict__ VB){
  __shared__ float XR[4][64], KR[4][64], VR[4][64];
  int t = threadIdx.x;
  int rl = t>>6, d = t&63;
  int r  = blockIdx.x*4 + rl;                // r = b*256+m == conf cell
  if (d == 0){
    float cn = ccnt[r];
    conf[r] = (cn > 0.f) ? csum[r]/(cn+1e-6f) : 0.f;
  }
  float v = srb[d];
  #pragma unroll
  for (int ps=0; ps<16; ++ps)
    v += part[(size_t)ps*2048*64 + r*64 + d];
  float s = v;
  #pragma unroll
  for (int off=32; off; off>>=1) s += __shfl_xor(s, off, 64);
  float mean = s*(1.f/64.f);
  float dd = v - mean;
  float s2 = dd*dd;
  #pragma unroll
  for (int off=32; off; off>>=1) s2 += __shfl_xor(s2, off, 64);
  float var = s2*(1.f/64.f);
  XR[rl][d] = dd*(1.f/sqrtf(var+1e-5f))*nw[d] + nbv[d];
  __syncthreads();
  float ka=0.f, va=0.f;
  for (int cc=0; cc<64; ++cc){
    float xc = XR[rl][cc];
    ka += xc*kvw[d*64+cc];
    va += xc*kvw[(64+d)*64+cc];
  }
  KR[rl][d] = ka; VR[rl][d] = va;
  __syncthreads();
  int c = d;
  float ak=0.f, av=0.f;
  for (int i=0;i<64;++i){
    ak += KR[rl][i]*qw[i*64+c];
    av += VR[rl][i]*pw[c*64+i];
  }
  int b = r>>8, m = r&255;
  {
    int nt = m>>4, l15 = m&15, kb = c>>5, h = (c>>3)&3, j = c&7;
    KB[((((b*16 + nt)*2 + kb)*4 + h)*16 + l15)*8 + j] = f2bf(ak);
  }
  {
    int ct = c>>4, n15 = c&15, kb2 = m>>5, h2 = (m>>3)&3, j2 = m&7;
    VB[((((b*4 + ct)*8 + kb2)*4 + h2)*16 + n15)*8 + j2] = f2bf(av);
  }
}

// fallback MFMA attention (monolithic, proven)
__global__ __launch_bounds__(256) void k_attn5(
    const float* __restrict__ x, const ushort* __restrict__ KB,
    const ushort* __restrict__ VB, const float* __restrict__ conf,
    const float* __restrict__ projb, float* __restrict__ out){
  alignas(16) __shared__ ushort P[4*4096];
  int t = threadIdx.x, w = t>>6, l = t&63;
  int b = blockIdx.x >> 8;
  int row0 = ((blockIdx.x & 255) << 6) + (w<<4);
  int l15 = l & 15, h = l >> 4;
  const ushort* KBb = KB + b*16384;
  const ushort* VBb = VB + b*16384;
  bf16x8 xa[2];
  {
    const float* xr = x + (size_t)(b*NN + row0 + l15)*64 + h*8;
    #pragma unroll
    for (int kb=0; kb<2; ++kb){
      float4 a0 = *(const float4*)(xr + 32*kb);
      float4 a1 = *(const float4*)(xr + 32*kb + 4);
      bf16x8 v;
      v[0]=(short)f2bf(a0.x); v[1]=(short)f2bf(a0.y);
      v[2]=(short)f2bf(a0.z); v[3]=(short)f2bf(a0.w);
      v[4]=(short)f2bf(a1.x); v[5]=(short)f2bf(a1.y);
      v[6]=(short)f2bf(a1.z); v[7]=(short)f2bf(a1.w);
      xa[kb]=v;
    }
  }
  f32x4 acc[16];
  #pragma unroll
  for (int nt=0;nt<16;++nt) acc[nt] = (f32x4){0.f,0.f,0.f,0.f};
  #pragma unroll
  for (int nt=0;nt<16;++nt){
    bf16x8 b0 = *(const bf16x8*)(KBb + (nt*2+0)*512 + l*8);
    bf16x8 b1 = *(const bf16x8*)(KBb + (nt*2+1)*512 + l*8);
    acc[nt] = __builtin_amdgcn_mfma_f32_16x16x32_bf16(xa[0], b0, acc[nt], 0,0,0);
    acc[nt] = __builtin_amdgcn_mfma_f32_16x16x32_bf16(xa[1], b1, acc[nt], 0,0,0);
  }
  float rs[4] = {0.f,0.f,0.f,0.f};
  ushort* Pw = P + w*4096;
  #pragma unroll
  for (int nt=0;nt<16;++nt){
    float cf = conf[b*GM + nt*16 + l15];
    #pragma unroll
    for (int reg=0;reg<4;++reg){
      float p = __expf(fmaf(acc[nt][reg], 0.125f, cf));
      rs[reg] += p;
      int m   = nt*16 + l15;
      int row = h*4 + reg;
      int ld  = ((m>>3)&3)*16 + row;
      int idx = ((m>>5)*512 + ld*8 + (m&7)) ^ (ld & 0x38);
      Pw[idx] = f2bf(p);
    }
  }
  #pragma unroll
  for (int off=1; off<16; off<<=1){
    #pragma unroll
    for (int reg=0;reg<4;++reg) rs[reg] += __shfl_xor(rs[reg], off, 64);
  }
  f32x4 oacc[4];
  #pragma unroll
  for (int ct=0;ct<4;++ct) oacc[ct] = (f32x4){0.f,0.f,0.f,0.f};
  #pragma unroll
  for (int kb2=0;kb2<8;++kb2){
    int ridx = (kb2*512 + l*8) ^ (l & 0x38);
    bf16x8 pa = *(const bf16x8*)(Pw + ridx);
    #pragma unroll
    for (int ct=0;ct<4;++ct){
      bf16x8 vb = *(const bf16x8*)(VBb + (ct*8+kb2)*512 + l*8);
      oacc[ct] = __builtin_amdgcn_mfma_f32_16x16x32_bf16(pa, vb, oacc[ct], 0,0,0);
    }
  }
  float* OT = (float*)Pw;
  #pragma unroll
  for (int ct=0;ct<4;++ct){
    float pb4 = projb[ct*16 + l15];
    #pragma unroll
    for (int reg=0;reg<4;++reg)
      OT[(h*4+reg)*68 + ct*16 + l15] = oacc[ct][reg]/rs[reg] + pb4;
  }
  #pragma unroll
  for (int i=0;i<4;++i){
    int row = i*4 + h;
    float4 v = *(const float4*)&OT[row*68 + l15*4];
    *(float4*)&out[(size_t)(b*NN + row0 + row)*64 + l15*4] = v;
  }
}

// ---------- attn8: attn6 re-partitioned to 1-wave blocks ----------
__global__ __launch_bounds__(64) void k_attn8(
    const float* __restrict__ x, const ushort* __restrict__ KB,
    const ushort* __restrict__ VB, const float* __restrict__ conf,
    const float* __restrict__ projb, float* __restrict__ out){
  alignas(16) __shared__ ushort Pw[4096];      // 8 KB, wave-private
  int l = threadIdx.x;
  int b = blockIdx.x >> 10;
  int row0 = (blockIdx.x & 1023) << 4;
  int l15 = l & 15, h = l >> 4;
  const ushort* KBb = KB + b*16384;
  const ushort* VBb = VB + b*16384;

  bf16x8 xa[2];
  {
    const float* xr = x + (size_t)(b*NN + row0 + l15)*64 + h*8;
    #pragma unroll
    for (int kb=0; kb<2; ++kb){
      float4 a0 = *(const float4*)(xr + 32*kb);
      float4 a1 = *(const float4*)(xr + 32*kb + 4);
      bf16x8 v;
      v[0]=(short)f2bf(a0.x); v[1]=(short)f2bf(a0.y);
      v[2]=(short)f2bf(a0.z); v[3]=(short)f2bf(a0.w);
      v[4]=(short)f2bf(a1.x); v[5]=(short)f2bf(a1.y);
      v[6]=(short)f2bf(a1.z); v[7]=(short)f2bf(a1.w);
      xa[kb]=v;
    }
  }

  float rs[4] = {0.f,0.f,0.f,0.f};
  f32x4 oacc[4];
  #pragma unroll
  for (int ct=0;ct<4;++ct) oacc[ct] = (f32x4){0.f,0.f,0.f,0.f};

  #pragma unroll
  for (int c=0;c<4;++c){
    f32x4 acc[4];
    #pragma unroll
    for (int q=0;q<4;++q) acc[q] = (f32x4){0.f,0.f,0.f,0.f};
    #pragma unroll
    for (int q=0;q<4;++q){
      int nt = c*4 + q;
      bf16x8 b0 = *(const bf16x8*)(KBb + (nt*2+0)*512 + l*8);
      bf16x8 b1 = *(const bf16x8*)(KBb + (nt*2+1)*512 + l*8);
      acc[q] = __builtin_amdgcn_mfma_f32_16x16x32_bf16(xa[0], b0, acc[q], 0,0,0);
      acc[q] = __builtin_amdgcn_mfma_f32_16x16x32_bf16(xa[1], b1, acc[q], 0,0,0);
    }
    #pragma unroll
    for (int q=0;q<4;++q){
      int nt = c*4 + q;
      float cf = conf[b*GM + nt*16 + l15];
      #pragma unroll
      for (int reg=0;reg<4;++reg){
        float p = __expf(fmaf(acc[q][reg], 0.125f, cf));
        rs[reg] += p;
        int m   = nt*16 + l15;
        int row = h*4 + reg;
        int ld  = ((m>>3)&3)*16 + row;
        int idx = ((m>>5)*512 + ld*8 + (m&7)) ^ (ld & 0x38);
        Pw[idx] = f2bf(p);
      }
    }
    #pragma unroll
    for (int kk=0;kk<2;++kk){
      int kb2 = c*2 + kk;
      int ridx = (kb2*512 + l*8) ^ (l & 0x38);
      bf16x8 pa = *(const bf16x8*)(Pw + ridx);
      #pragma unroll
      for (int ct=0;ct<4;++ct){
        bf16x8 vb = *(const bf16x8*)(VBb + (ct*8+kb2)*512 + l*8);
        oacc[ct] = __builtin_amdgcn_mfma_f32_16x16x32_bf16(pa, vb, oacc[ct], 0,0,0);
      }
    }
  }

  #pragma unroll
  for (int off=1; off<16; off<<=1){
    #pragma unroll
    for (int reg=0;reg<4;++reg) rs[reg] += __shfl_xor(rs[reg], off, 64);
  }

  float* OT = (float*)Pw;
  #pragma unroll
  for (int ct=0;ct<4;++ct){
    float pb4 = projb[ct*16 + l15];
    #pragma unroll
    for (int reg=0;reg<4;++reg)
      OT[(h*4+reg)*68 + ct*16 + l15] = oacc[ct][reg]/rs[reg] + pb4;
  }
  #pragma unroll
  for (int i=0;i<4;++i){
    int row = i*4 + h;
    float4 v = *(const float4*)&OT[row*68 + l15*4];
    *(float4*)&out[(size_t)(b*NN + row0 + row)*64 + l15*4] = v;
  }
}

extern "C" void kernel_launch(void* const* d_in, const int* in_sizes, int n_in,
                              void* d_out, int out_size, void* d_ws, size_t ws_size,
                              hipStream_t stream){
  const float* x    = (const float*)d_in[0];
  const float* xsrc = (const float*)d_in[1];
  const float* loc  = (const float*)d_in[2];
  const float* csrc = (const float*)d_in[3];
  const float* qw   = (const float*)d_in[4];
  const float* kvw  = (const float*)d_in[5];
  const float* srw  = (const float*)d_in[6];
  const float* srb  = (const float*)d_in[7];
  const float* nw   = (const float*)d_in[8];
  const float* nbv  = (const float*)d_in[9];
  const float* pw   = (const float*)d_in[10];
  const float* pb   = (const float*)d_in[11];
  float* out = (float*)d_out;
  float* ws = (float*)d_ws;

  // ===== primary layout (all 8-batch, separable fill, conv partials) =====
  size_t of_feat  = 0;
  size_t of_cnt   = of_feat  + 8ull*GH*GW*NC;
  size_t of_csum  = of_cnt   + 8ull*GH*GW;
  size_t of_ccnt  = of_csum  + 8ull*GM;
  size_t zero_end = of_ccnt  + 8ull*GM;
  size_t of_feath = zero_end;
  size_t of_maskh = of_feath + 8ull*GH*GW*NC;
  size_t of_part  = of_maskh + 8ull*GH*GW;
  size_t of_conf  = of_part  + 16ull*2048*64;
  size_t of_kb    = of_conf  + 8ull*GM;
  size_t of_vb    = of_kb    + 8ull*8192;
  size_t total_p  = of_vb    + 8ull*8192;

  if (ws_size >= total_p*sizeof(float)){
    k_zero         <<<2048,        256, 0, stream>>>((float4*)ws, (int)(zero_end>>2));
    k_scatter_feat <<<8*NN*NC/256, 256, 0, stream>>>(xsrc, loc, ws+of_feat);
    k_scatter_aux  <<<8*NN/256,    256, 0, stream>>>(loc, csrc, ws+of_cnt, ws+of_csum, ws+of_ccnt);
    k_finfillh     <<<8*GH,        256, 0, stream>>>(ws+of_feat, ws+of_cnt, ws+of_feath, ws+of_maskh);
    k_fillv        <<<8*GH,        256, 0, stream>>>(ws+of_feat, ws+of_cnt, ws+of_feath, ws+of_maskh);
    dim3 gconv(32, 8, 2);
    k_srconv2      <<<gconv,       256, 0, stream>>>(ws+of_feat, srw, ws+of_part);
    k_kvfused2     <<<8*GM/4,      256, 0, stream>>>(ws+of_part, srb, nw, nbv, kvw, qw, pw,
                                                     ws+of_csum, ws+of_ccnt, ws+of_conf,
                                                     (ushort*)(ws+of_kb), (ushort*)(ws+of_vb));
    k_attn8        <<<8*NN/16,     64,  0, stream>>>(x, (const ushort*)(ws+of_kb),
                                                     (const ushort*)(ws+of_vb),
                                                     ws+of_conf, pb, out);
  } else {
    // ---------------- fallback: exact round-10 8-batch path ----------------
    size_t f_feat = 0;
    size_t f_cnt  = f_feat + 8ull*GH*GW*NC;
    size_t f_csum = f_cnt  + 8ull*GH*GW;
    size_t f_ccnt = f_csum + 8ull*GM;
    size_t f_xs0  = f_ccnt + 8ull*GM;
    size_t f_zero = f_xs0  + 8ull*GM*NC;
    size_t f_conf = f_zero;
    size_t f_xs   = f_conf + 8ull*GM;
    size_t f_kr   = f_xs   + 8ull*GM*NC;
    size_t f_vr   = f_kr   + 8ull*GM*NC;
    size_t f_kb   = f_vr   + 8ull*GM*NC;
    size_t f_vb   = f_kb   + 8ull*8192;
    hipMemsetAsync(ws, 0, f_zero*sizeof(float), stream);
    k_scatter_feat <<<8*NN*NC/256, 256, 0, stream>>>(xsrc, loc, ws+f_feat);
    k_scatter_aux  <<<8*NN/256,    256, 0, stream>>>(loc, csrc, ws+f_cnt, ws+f_csum, ws+f_ccnt);
    k_finalize_feat<<<8*GH*GW*NC/256, 256, 0, stream>>>(ws+f_feat, ws+f_cnt);
    k_finalize_conf<<<8*GM/256,    256, 0, stream>>>(ws+f_csum, ws+f_ccnt, ws+f_conf);
    k_fill2        <<<8*GH*GW*4/256, 256, 0, stream>>>(ws+f_cnt, ws+f_feat);
    dim3 gconv(8*GM/64, 8);
    k_srconv       <<<gconv,       256, 0, stream>>>(ws+f_feat, srw, ws+f_xs0);
    k_ln           <<<8*GM/4,      256, 0, stream>>>(ws+f_xs0, srb, nw, nbv, ws+f_xs);
    k_kv1          <<<8*GM*NC/256, 256, 0, stream>>>(ws+f_xs, kvw, ws+f_kr, ws+f_vr);
    k_kvproj2      <<<8*GM*NC/256, 256, 0, stream>>>(ws+f_kr, ws+f_vr, qw, pw,
                                                     (ushort*)(ws+f_kb), (ushort*)(ws+f_vb));
    k_attn5        <<<8*NN/64,     256, 0, stream>>>(x, (const ushort*)(ws+f_kb),
                                                     (const ushort*)(ws+f_vb),
                                                     ws+f_conf, pb, out);
  }
}

// Round 20
// 177.923 us; speedup vs baseline: 1.4444x; 1.0183x over previous
//
#include <hip/hip_runtime.h>
#include <hip/hip_bf16.h>

#define NN 16384
#define NC 64
#define GH 128
#define GW 128
#define GM 256

typedef __attribute__((ext_vector_type(8))) short bf16x8;
typedef __attribute__((ext_vector_type(4))) float f32x4;

static __device__ __forceinline__ int reflect128(int i){
  if (i < 0) i = -i;
  if (i > 127) i = 254 - i;
  return i;
}

// native RNE cast: compiler packs adjacent pairs into v_cvt_pk_bf16_f32
static __device__ __forceinline__ ushort f2bf(float f){
  __hip_bfloat16 h = __float2bfloat16(f);
  union { __hip_bfloat16 h; ushort u; } v; v.h = h;
  return v.u;
}

// px = round(0.5*(loc+1)*S - 0.5): bit-exact replica of reference f32 sequence
static __device__ __forceinline__ int cell_of(float l, float S2, int hi){
  l = fminf(fmaxf(l, -1.f), 1.f);
  float u = l + 1.f;
  int p = (int)rintf(u*S2 - 0.5f);
  return min(max(p,0),hi);
}

// grid-stride float4 zero
__global__ __launch_bounds__(256) void k_zero(float4* __restrict__ p, int n4){
  int i = blockIdx.x*256 + threadIdx.x;
  int stride = gridDim.x*256;
  float4 z = make_float4(0.f,0.f,0.f,0.f);
  for (; i < n4; i += stride) p[i] = z;
}

// scatter feat (blocks [0,32768)) + aux cnt/csum/ccnt (blocks [32768,33280))
// merged at BLOCK granularity: both paths keep full-wave atomic shape
// (round-18 lesson: never demote per-token atomics to single-lane).
__global__ __launch_bounds__(256) void k_scatter_all(
    const float* __restrict__ xsrc, const float* __restrict__ loc,
    const float* __restrict__ csrc, float* __restrict__ featg,
    float* __restrict__ cnt, float* __restrict__ csum, float* __restrict__ ccnt){
  if (blockIdx.x < 8*NN*NC/256){
    int gid = blockIdx.x*256 + threadIdx.x;
    int t = gid >> 6;
    int b = t >> 14;
    int px = cell_of(loc[2*t],   64.f, 127);
    int py = cell_of(loc[2*t+1], 64.f, 127);
    int cell = (b*GH + py)*GW + px;
    atomicAdd(&featg[cell*NC + (gid & 63)], xsrc[gid]);
  } else {
    int t = (blockIdx.x - 8*NN*NC/256)*256 + threadIdx.x;
    int b = t >> 14;
    int px = cell_of(loc[2*t],   64.f, 127);
    int py = cell_of(loc[2*t+1], 64.f, 127);
    atomicAdd(&cnt[(b*GH+py)*GW+px], 1.0f);
    int qx = cell_of(loc[2*t],   8.f, 15);
    int qy = cell_of(loc[2*t+1], 8.f, 15);
    int cell = b*GM + qy*16 + qx;
    atomicAdd(&csum[cell], csrc[t]);
    atomicAdd(&ccnt[cell], 1.0f);
  }
}

// fallback kernels (round-10 path) --------------------------------------
__global__ __launch_bounds__(256) void k_scatter_feat(
    const float* __restrict__ xsrc, const float* __restrict__ loc,
    float* __restrict__ featg){
  int gid = blockIdx.x*256 + threadIdx.x;
  int t = gid >> 6;
  int b = t >> 14;
  int px = cell_of(loc[2*t],   64.f, 127);
  int py = cell_of(loc[2*t+1], 64.f, 127);
  int cell = (b*GH + py)*GW + px;
  atomicAdd(&featg[cell*NC + (gid & 63)], xsrc[gid]);
}

__global__ __launch_bounds__(256) void k_scatter_aux(
    const float* __restrict__ loc, const float* __restrict__ csrc,
    float* __restrict__ cnt, float* __restrict__ csum, float* __restrict__ ccnt){
  int t = blockIdx.x*256 + threadIdx.x;
  int b = t >> 14;
  int px = cell_of(loc[2*t],   64.f, 127);
  int py = cell_of(loc[2*t+1], 64.f, 127);
  atomicAdd(&cnt[(b*GH+py)*GW+px], 1.0f);
  int qx = cell_of(loc[2*t],   8.f, 15);
  int qy = cell_of(loc[2*t+1], 8.f, 15);
  int cell = b*GM + qy*16 + qx;
  atomicAdd(&csum[cell], csrc[t]);
  atomicAdd(&ccnt[cell], 1.0f);
}

__global__ __launch_bounds__(256) void k_finalize_feat(
    float* __restrict__ featg, const float* __restrict__ cnt){
  int gid = blockIdx.x*256 + threadIdx.x;
  float cn = cnt[gid>>6];
  float v  = featg[gid];
  featg[gid] = (cn > 0.f) ? v/(cn+1e-6f) : 0.f;
}

__global__ __launch_bounds__(256) void k_finalize_conf(
    const float* __restrict__ csum, const float* __restrict__ ccnt,
    float* __restrict__ conf){
  int i = blockIdx.x*256 + threadIdx.x;
  float cn = ccnt[i];
  conf[i] = (cn > 0.f) ? csum[i]/(cn+1e-6f) : 0.f;
}

__global__ __launch_bounds__(256) void k_fill2(
    const float* __restrict__ cnt, float* __restrict__ feat){
  int gid = blockIdx.x*256 + threadIdx.x;
  int p = gid >> 2, cg = gid & 3;
  if (cnt[p] > 0.f) return;
  int b = p>>14, py=(p>>7)&127, px=p&127;
  const float fn = 0.039788735772973836f;
  float g1[9];
  #pragma unroll
  for (int i=0;i<9;++i){ float d=(float)i-4.f; g1[i]=__expf(-d*d*0.125f); }
  float4 acc[4];
  #pragma unroll
  for (int i=0;i<4;++i) acc[i]=make_float4(0.f,0.f,0.f,0.f);
  float msum=0.f;
  for (int dy=0; dy<9; ++dy){
    int iy = reflect128(py-4+dy);
    for (int dx=0; dx<9; ++dx){
      int ix = reflect128(px-4+dx);
      int q  = (b*GH+iy)*GW+ix;
      if (cnt[q] <= 0.f) continue;
      float wn = g1[dy]*g1[dx]*fn;
      msum += wn;
      const float4* fr = (const float4*)&feat[q*NC + cg*16];
      #pragma unroll
      for (int k=0;k<4;++k){
        float4 vv = fr[k];
        acc[k].x += wn*vv.x; acc[k].y += wn*vv.y;
        acc[k].z += wn*vv.z; acc[k].w += wn*vv.w;
      }
    }
  }
  if (msum <= 0.f) return;
  float inv = 1.f/(msum + 1e-6f);
  float4* o = (float4*)&feat[p*NC + cg*16];
  #pragma unroll
  for (int k=0;k<4;++k)
    o[k] = make_float4(acc[k].x*inv, acc[k].y*inv, acc[k].z*inv, acc[k].w*inv);
}

// ---------- separable fill, 8-batch, XCD-swizzled (T1) ----------
static __device__ __forceinline__ int rowswz(int bid){
  return ((bid & 7) << 7) + (bid >> 3);
}

__global__ __launch_bounds__(256) void k_finfillh(
    float* __restrict__ feat, const float* __restrict__ cnt,
    float* __restrict__ feath, float* __restrict__ maskh){
  __shared__ float F[GW*NC];                 // finalized row, 32 KB
  __shared__ float CR[GW];
  int py = rowswz(blockIdx.x), t = threadIdx.x;
  const float fn = 0.039788735772973836f;    // 1/(2*pi*var), var=4
  float g1n[9];
  #pragma unroll
  for (int i=0;i<9;++i){ float d=(float)i-4.f; g1n[i]=__expf(-d*d*0.125f)*fn; }
  if (t < GW) CR[t] = cnt[py*GW + t];
  __syncthreads();
  for (int i=t*4; i<GW*NC; i+=1024){
    int px = i>>6;
    float cn = CR[px];
    float inv = (cn > 0.f) ? 1.f/(cn+1e-6f) : 0.f;
    float4 v = *(const float4*)&feat[(size_t)py*GW*NC + i];
    v.x*=inv; v.y*=inv; v.z*=inv; v.w*=inv;
    *(float4*)&F[i] = v;
    *(float4*)&feat[(size_t)py*GW*NC + i] = v;
  }
  __syncthreads();
  for (int i=t*4; i<GW*NC; i+=1024){
    int px = i>>6, c = i&63;
    float4 acc = make_float4(0.f,0.f,0.f,0.f);
    #pragma unroll
    for (int dx=0; dx<9; ++dx){
      int ix = reflect128(px-4+dx);
      float w = g1n[dx];
      float4 v = *(const float4*)&F[ix*NC + c];
      acc.x += w*v.x; acc.y += w*v.y; acc.z += w*v.z; acc.w += w*v.w;
    }
    *(float4*)&feath[(size_t)py*GW*NC + i] = acc;
  }
  if (t < GW){
    float hm = 0.f;
    #pragma unroll
    for (int dx=0; dx<9; ++dx){
      int ix = reflect128(t-4+dx);
      hm += g1n[dx]*((CR[ix] > 0.f) ? 1.f : 0.f);
    }
    maskh[py*GW + t] = hm;
  }
}

__global__ __launch_bounds__(256) void k_fillv(
    float* __restrict__ feat, const float* __restrict__ cnt,
    const float* __restrict__ feath, const float* __restrict__ maskh){
  int pyg = rowswz(blockIdx.x), t = threadIdx.x;
  int b = pyg >> 7, pyl = pyg & 127;
  int px = t>>1, c0 = (t&1)<<5;
  float g1[9];
  #pragma unroll
  for (int i=0;i<9;++i){ float d=(float)i-4.f; g1[i]=__expf(-d*d*0.125f); }
  float cn = cnt[pyg*GW + px];
  float ym = 0.f;
  int ry[9];
  #pragma unroll
  for (int dy=0; dy<9; ++dy){
    ry[dy] = b*GH + reflect128(pyl-4+dy);
    ym += g1[dy]*maskh[ry[dy]*GW + px];
  }
  if (cn > 0.f || ym <= 0.f) return;
  float inv = 1.f/(ym + 1e-6f);
  float4 acc[8];
  #pragma unroll
  for (int k=0;k<8;++k) acc[k]=make_float4(0.f,0.f,0.f,0.f);
  #pragma unroll
  for (int dy=0; dy<9; ++dy){
    float w = g1[dy];
    const float4* hf = (const float4*)&feath[((size_t)ry[dy]*GW+px)*NC + c0];
    #pragma unroll
    for (int k=0;k<8;++k){
      float4 v = hf[k];
      acc[k].x += w*v.x; acc[k].y += w*v.y; acc[k].z += w*v.z; acc[k].w += w*v.w;
    }
  }
  float4* o = (float4*)&feat[((size_t)pyg*GW+px)*NC + c0];
  #pragma unroll
  for (int k=0;k<8;++k)
    o[k] = make_float4(acc[k].x*inv, acc[k].y*inv, acc[k].z*inv, acc[k].w*inv);
}

// ---------- fallback srconv (atomic split-K, proven) ----------
__global__ __launch_bounds__(256) void k_srconv(
    const float* __restrict__ feat, const float* __restrict__ srw,
    float* __restrict__ xs0){
  alignas(16) __shared__ float A[64*65];
  alignas(16) __shared__ float Bs[64*64];
  int mt = blockIdx.x, kh = blockIdx.y;
  int t = threadIdx.x;
  int tm = t>>4, tn = t&15;
  float acc[4][4] = {{0.f}};
  for (int kc=0; kc<8; ++kc){
    __syncthreads();
    for (int idx=t; idx<4096; idx+=256){
      int mr = idx>>6, kk = idx&63;
      int m = mt*64+mr;
      int b = m>>8, oh=(m>>4)&15, ow=m&15;
      A[mr*65+kk] = feat[(((b*GH)+(oh*8+kh))*GW + ow*8)*NC + kc*64 + kk];
    }
    for (int idx=t; idx<4096; idx+=256)
      Bs[idx] = srw[(kh*512 + kc*64)*64 + idx];
    __syncthreads();
    for (int kk=0; kk<64; ++kk){
      float4 bv = *(const float4*)&Bs[kk*64 + tn*4];
      #pragma unroll
      for (int i=0;i<4;++i){
        float av = A[(tm*4+i)*65 + kk];
        acc[i][0] += av*bv.x; acc[i][1] += av*bv.y;
        acc[i][2] += av*bv.z; acc[i][3] += av*bv.w;
      }
    }
  }
  #pragma unroll
  for (int i=0;i<4;++i)
    #pragma unroll
    for (int j=0;j<4;++j)
      atomicAdd(&xs0[(mt*64+tm*4+i)*64 + tn*4+j], acc[i][j]);
}

// ---------- srconv2: no atomics, 512 blocks, partials ----------
__global__ __launch_bounds__(256) void k_srconv2(
    const float* __restrict__ feat, const float* __restrict__ srw,
    float* __restrict__ part){
  alignas(16) __shared__ float A[64*65];
  alignas(16) __shared__ float Bs[64*64];
  int mt = blockIdx.x, kh = blockIdx.y, kq = blockIdx.z;
  int t = threadIdx.x;
  int tm = t>>4, tn = t&15;
  float acc[4][4] = {{0.f}};
  for (int kc=0; kc<4; ++kc){
    int kw = kq*4 + kc;
    __syncthreads();
    for (int idx=t; idx<4096; idx+=256){
      int mr = idx>>6, kk = idx&63;
      int m = mt*64+mr;
      int b = m>>8, oh=(m>>4)&15, ow=m&15;
      A[mr*65+kk] = feat[(((b*GH)+(oh*8+kh))*GW + ow*8 + kw)*NC + kk];
    }
    for (int idx=t; idx<4096; idx+=256)
      Bs[idx] = srw[(kh*512 + kw*64)*64 + idx];
    __syncthreads();
    for (int kk=0; kk<64; ++kk){
      float4 bv = *(const float4*)&Bs[kk*64 + tn*4];
      #pragma unroll
      for (int i=0;i<4;++i){
        float av = A[(tm*4+i)*65 + kk];
        acc[i][0] += av*bv.x; acc[i][1] += av*bv.y;
        acc[i][2] += av*bv.z; acc[i][3] += av*bv.w;
      }
    }
  }
  float* pdst = part + (size_t)(kh*2+kq)*2048*64;
  #pragma unroll
  for (int i=0;i<4;++i)
    #pragma unroll
    for (int j=0;j<4;++j)
      pdst[(mt*64+tm*4+i)*64 + tn*4+j] = acc[i][j];
}

// fallback layernorm (reads xs0)
__global__ __launch_bounds__(256) void k_ln(
    const float* __restrict__ xs0, const float* __restrict__ srb,
    const float* __restrict__ nw, const float* __restrict__ nbv,
    float* __restrict__ xs){
  int row  = blockIdx.x*4 + (threadIdx.x>>6);
  int lane = threadIdx.x & 63;
  float v = xs0[row*64+lane] + srb[lane];
  float s = v;
  #pragma unroll
  for (int off=32; off; off>>=1) s += __shfl_xor(s, off, 64);
  float mean = s*(1.f/64.f);
  float d = v - mean;
  float s2 = d*d;
  #pragma unroll
  for (int off=32; off; off>>=1) s2 += __shfl_xor(s2, off, 64);
  float var = s2*(1.f/64.f);
  xs[row*64+lane] = d*(1.f/sqrtf(var+1e-5f))*nw[lane] + nbv[lane];
}

// fallback kv kernels
__global__ __launch_bounds__(256) void k_kv1(
    const float* __restrict__ xs, const float* __restrict__ kvw,
    float* __restrict__ kraw, float* __restrict__ vraw){
  int gid = blockIdx.x*256 + threadIdx.x;
  int r = gid >> 6, d = gid & 63;
  const float* xr = &xs[r*64];
  float ka=0.f, va=0.f;
  for (int c=0;c<64;++c){
    float xc = xr[c];
    ka += xc*kvw[d*64+c];
    va += xc*kvw[(64+d)*64+c];
  }
  kraw[gid] = ka;
  vraw[gid] = va;
}

__global__ __launch_bounds__(256) void k_kvproj2(
    const float* __restrict__ kraw, const float* __restrict__ vraw,
    const float* __restrict__ qw, const float* __restrict__ pw,
    ushort* __restrict__ KB, ushort* __restrict__ VB){
  int gid = blockIdx.x*256 + threadIdx.x;
  int r = gid >> 6, c = gid & 63;
  int b = r >> 8, m = r & 255;
  const float* kr = &kraw[r*64];
  const float* vr = &vraw[r*64];
  float ak=0.f, av=0.f;
  for (int i=0;i<64;++i){
    ak += kr[i]*qw[i*64+c];
    av += vr[i]*pw[c*64+i];
  }
  {
    int nt = m>>4, l15 = m&15, kb = c>>5, h = (c>>3)&3, j = c&7;
    KB[((((b*16 + nt)*2 + kb)*4 + h)*16 + l15)*8 + j] = f2bf(ak);
  }
  {
    int ct = c>>4, n15 = c&15, kb2 = m>>5, h2 = (m>>3)&3, j2 = m&7;
    VB[((((b*4 + ct)*8 + kb2)*4 + h2)*16 + n15)*8 + j2] = f2bf(av);
  }
}

// ---- fused LN + kv + proj-fold + pack + (folded) conf finalize ----
__global__ __launch_bounds__(256) void k_kvfused2(
    const float* __restrict__ part, const float* __restrict__ srb,
    const float* __restrict__ nw, const float* __restrict__ nbv,
    const float* __restrict__ kvw, const float* __restrict__ qw,
    const float* __restrict__ pw,
    const float* __restrict__ csum, const float* __restrict__ ccnt,
    float* __restrict__ conf,
    ushort* __restrict__ KB, ushort* __restrict__ VB){
  __shared__ float XR[4][64], KR[4][64], VR[4][64];
  int t = threadIdx.x;
  int rl = t>>6, d = t&63;
  int r  = blockIdx.x*4 + rl;                // r = b*256+m == conf cell
  if (d == 0){
    float cn = ccnt[r];
    conf[r] = (cn > 0.f) ? csum[r]/(cn+1e-6f) : 0.f;
  }
  float v = srb[d];
  #pragma unroll
  for (int ps=0; ps<16; ++ps)
    v += part[(size_t)ps*2048*64 + r*64 + d];
  float s = v;
  #pragma unroll
  for (int off=32; off; off>>=1) s += __shfl_xor(s, off, 64);
  float mean = s*(1.f/64.f);
  float dd = v - mean;
  float s2 = dd*dd;
  #pragma unroll
  for (int off=32; off; off>>=1) s2 += __shfl_xor(s2, off, 64);
  float var = s2*(1.f/64.f);
  XR[rl][d] = dd*(1.f/sqrtf(var+1e-5f))*nw[d] + nbv[d];
  __syncthreads();
  float ka=0.f, va=0.f;
  for (int cc=0; cc<64; ++cc){
    float xc = XR[rl][cc];
    ka += xc*kvw[d*64+cc];
    va += xc*kvw[(64+d)*64+cc];
  }
  KR[rl][d] = ka; VR[rl][d] = va;
  __syncthreads();
  int c = d;
  float ak=0.f, av=0.f;
  for (int i=0;i<64;++i){
    ak += KR[rl][i]*qw[i*64+c];
    av += VR[rl][i]*pw[c*64+i];
  }
  int b = r>>8, m = r&255;
  {
    int nt = m>>4, l15 = m&15, kb = c>>5, h = (c>>3)&3, j = c&7;
    KB[((((b*16 + nt)*2 + kb)*4 + h)*16 + l15)*8 + j] = f2bf(ak);
  }
  {
    int ct = c>>4, n15 = c&15, kb2 = m>>5, h2 = (m>>3)&3, j2 = m&7;
    VB[((((b*4 + ct)*8 + kb2)*4 + h2)*16 + n15)*8 + j2] = f2bf(av);
  }
}

// fallback MFMA attention (monolithic, proven)
__global__ __launch_bounds__(256) void k_attn5(
    const float* __restrict__ x, const ushort* __restrict__ KB,
    const ushort* __restrict__ VB, const float* __restrict__ conf,
    const float* __restrict__ projb, float* __restrict__ out){
  alignas(16) __shared__ ushort P[4*4096];
  int t = threadIdx.x, w = t>>6, l = t&63;
  int b = blockIdx.x >> 8;
  int row0 = ((blockIdx.x & 255) << 6) + (w<<4);
  int l15 = l & 15, h = l >> 4;
  const ushort* KBb = KB + b*16384;
  const ushort* VBb = VB + b*16384;
  bf16x8 xa[2];
  {
    const float* xr = x + (size_t)(b*NN + row0 + l15)*64 + h*8;
    #pragma unroll
    for (int kb=0; kb<2; ++kb){
      float4 a0 = *(const float4*)(xr + 32*kb);
      float4 a1 = *(const float4*)(xr + 32*kb + 4);
      bf16x8 v;
      v[0]=(short)f2bf(a0.x); v[1]=(short)f2bf(a0.y);
      v[2]=(short)f2bf(a0.z); v[3]=(short)f2bf(a0.w);
      v[4]=(short)f2bf(a1.x); v[5]=(short)f2bf(a1.y);
      v[6]=(short)f2bf(a1.z); v[7]=(short)f2bf(a1.w);
      xa[kb]=v;
    }
  }
  f32x4 acc[16];
  #pragma unroll
  for (int nt=0;nt<16;++nt) acc[nt] = (f32x4){0.f,0.f,0.f,0.f};
  #pragma unroll
  for (int nt=0;nt<16;++nt){
    bf16x8 b0 = *(const bf16x8*)(KBb + (nt*2+0)*512 + l*8);
    bf16x8 b1 = *(const bf16x8*)(KBb + (nt*2+1)*512 + l*8);
    acc[nt] = __builtin_amdgcn_mfma_f32_16x16x32_bf16(xa[0], b0, acc[nt], 0,0,0);
    acc[nt] = __builtin_amdgcn_mfma_f32_16x16x32_bf16(xa[1], b1, acc[nt], 0,0,0);
  }
  float rs[4] = {0.f,0.f,0.f,0.f};
  ushort* Pw = P + w*4096;
  #pragma unroll
  for (int nt=0;nt<16;++nt){
    float cf = conf[b*GM + nt*16 + l15];
    #pragma unroll
    for (int reg=0;reg<4;++reg){
      float p = __expf(fmaf(acc[nt][reg], 0.125f, cf));
      rs[reg] += p;
      int m   = nt*16 + l15;
      int row = h*4 + reg;
      int ld  = ((m>>3)&3)*16 + row;
      int idx = ((m>>5)*512 + ld*8 + (m&7)) ^ (ld & 0x38);
      Pw[idx] = f2bf(p);
    }
  }
  #pragma unroll
  for (int off=1; off<16; off<<=1){
    #pragma unroll
    for (int reg=0;reg<4;++reg) rs[reg] += __shfl_xor(rs[reg], off, 64);
  }
  f32x4 oacc[4];
  #pragma unroll
  for (int ct=0;ct<4;++ct) oacc[ct] = (f32x4){0.f,0.f,0.f,0.f};
  #pragma unroll
  for (int kb2=0;kb2<8;++kb2){
    int ridx = (kb2*512 + l*8) ^ (l & 0x38);
    bf16x8 pa = *(const bf16x8*)(Pw + ridx);
    #pragma unroll
    for (int ct=0;ct<4;++ct){
      bf16x8 vb = *(const bf16x8*)(VBb + (ct*8+kb2)*512 + l*8);
      oacc[ct] = __builtin_amdgcn_mfma_f32_16x16x32_bf16(pa, vb, oacc[ct], 0,0,0);
    }
  }
  float* OT = (float*)Pw;
  #pragma unroll
  for (int ct=0;ct<4;++ct){
    float pb4 = projb[ct*16 + l15];
    #pragma unroll
    for (int reg=0;reg<4;++reg)
      OT[(h*4+reg)*68 + ct*16 + l15] = oacc[ct][reg]/rs[reg] + pb4;
  }
  #pragma unroll
  for (int i=0;i<4;++i){
    int row = i*4 + h;
    float4 v = *(const float4*)&OT[row*68 + l15*4];
    *(float4*)&out[(size_t)(b*NN + row0 + row)*64 + l15*4] = v;
  }
}

// ---------- attn8: attn6 re-partitioned to 1-wave blocks (proven r19) ----------
__global__ __launch_bounds__(64) void k_attn8(
    const float* __restrict__ x, const ushort* __restrict__ KB,
    const ushort* __restrict__ VB, const float* __restrict__ conf,
    const float* __restrict__ projb, float* __restrict__ out){
  alignas(16) __shared__ ushort Pw[4096];      // 8 KB, wave-private
  int l = threadIdx.x;
  int b = blockIdx.x >> 10;
  int row0 = (blockIdx.x & 1023) << 4;
  int l15 = l & 15, h = l >> 4;
  const ushort* KBb = KB + b*16384;
  const ushort* VBb = VB + b*16384;

  bf16x8 xa[2];
  {
    const float* xr = x + (size_t)(b*NN + row0 + l15)*64 + h*8;
    #pragma unroll
    for (int kb=0; kb<2; ++kb){
      float4 a0 = *(const float4*)(xr + 32*kb);
      float4 a1 = *(const float4*)(xr + 32*kb + 4);
      bf16x8 v;
      v[0]=(short)f2bf(a0.x); v[1]=(short)f2bf(a0.y);
      v[2]=(short)f2bf(a0.z); v[3]=(short)f2bf(a0.w);
      v[4]=(short)f2bf(a1.x); v[5]=(short)f2bf(a1.y);
      v[6]=(short)f2bf(a1.z); v[7]=(short)f2bf(a1.w);
      xa[kb]=v;
    }
  }

  float rs[4] = {0.f,0.f,0.f,0.f};
  f32x4 oacc[4];
  #pragma unroll
  for (int ct=0;ct<4;++ct) oacc[ct] = (f32x4){0.f,0.f,0.f,0.f};

  #pragma unroll
  for (int c=0;c<4;++c){
    f32x4 acc[4];
    #pragma unroll
    for (int q=0;q<4;++q) acc[q] = (f32x4){0.f,0.f,0.f,0.f};
    #pragma unroll
    for (int q=0;q<4;++q){
      int nt = c*4 + q;
      bf16x8 b0 = *(const bf16x8*)(KBb + (nt*2+0)*512 + l*8);
      bf16x8 b1 = *(const bf16x8*)(KBb + (nt*2+1)*512 + l*8);
      acc[q] = __builtin_amdgcn_mfma_f32_16x16x32_bf16(xa[0], b0, acc[q], 0,0,0);
      acc[q] = __builtin_amdgcn_mfma_f32_16x16x32_bf16(xa[1], b1, acc[q], 0,0,0);
    }
    #pragma unroll
    for (int q=0;q<4;++q){
      int nt = c*4 + q;
      float cf = conf[b*GM + nt*16 + l15];
      #pragma unroll
      for (int reg=0;reg<4;++reg){
        float p = __expf(fmaf(acc[q][reg], 0.125f, cf));
        rs[reg] += p;
        int m   = nt*16 + l15;
        int row = h*4 + reg;
        int ld  = ((m>>3)&3)*16 + row;
        int idx = ((m>>5)*512 + ld*8 + (m&7)) ^ (ld & 0x38);
        Pw[idx] = f2bf(p);
      }
    }
    #pragma unroll
    for (int kk=0;kk<2;++kk){
      int kb2 = c*2 + kk;
      int ridx = (kb2*512 + l*8) ^ (l & 0x38);
      bf16x8 pa = *(const bf16x8*)(Pw + ridx);
      #pragma unroll
      for (int ct=0;ct<4;++ct){
        bf16x8 vb = *(const bf16x8*)(VBb + (ct*8+kb2)*512 + l*8);
        oacc[ct] = __builtin_amdgcn_mfma_f32_16x16x32_bf16(pa, vb, oacc[ct], 0,0,0);
      }
    }
  }

  #pragma unroll
  for (int off=1; off<16; off<<=1){
    #pragma unroll
    for (int reg=0;reg<4;++reg) rs[reg] += __shfl_xor(rs[reg], off, 64);
  }

  float* OT = (float*)Pw;
  #pragma unroll
  for (int ct=0;ct<4;++ct){
    float pb4 = projb[ct*16 + l15];
    #pragma unroll
    for (int reg=0;reg<4;++reg)
      OT[(h*4+reg)*68 + ct*16 + l15] = oacc[ct][reg]/rs[reg] + pb4;
  }
  #pragma unroll
  for (int i=0;i<4;++i){
    int row = i*4 + h;
    float4 v = *(const float4*)&OT[row*68 + l15*4];
    *(float4*)&out[(size_t)(b*NN + row0 + row)*64 + l15*4] = v;
  }
}

extern "C" void kernel_launch(void* const* d_in, const int* in_sizes, int n_in,
                              void* d_out, int out_size, void* d_ws, size_t ws_size,
                              hipStream_t stream){
  const float* x    = (const float*)d_in[0];
  const float* xsrc = (const float*)d_in[1];
  const float* loc  = (const float*)d_in[2];
  const float* csrc = (const float*)d_in[3];
  const float* qw   = (const float*)d_in[4];
  const float* kvw  = (const float*)d_in[5];
  const float* srw  = (const float*)d_in[6];
  const float* srb  = (const float*)d_in[7];
  const float* nw   = (const float*)d_in[8];
  const float* nbv  = (const float*)d_in[9];
  const float* pw   = (const float*)d_in[10];
  const float* pb   = (const float*)d_in[11];
  float* out = (float*)d_out;
  float* ws = (float*)d_ws;

  // ===== primary layout (all 8-batch, separable fill, conv partials) =====
  size_t of_feat  = 0;
  size_t of_cnt   = of_feat  + 8ull*GH*GW*NC;
  size_t of_csum  = of_cnt   + 8ull*GH*GW;
  size_t of_ccnt  = of_csum  + 8ull*GM;
  size_t zero_end = of_ccnt  + 8ull*GM;
  size_t of_feath = zero_end;
  size_t of_maskh = of_feath + 8ull*GH*GW*NC;
  size_t of_part  = of_maskh + 8ull*GH*GW;
  size_t of_conf  = of_part  + 16ull*2048*64;
  size_t of_kb    = of_conf  + 8ull*GM;
  size_t of_vb    = of_kb    + 8ull*8192;
  size_t total_p  = of_vb    + 8ull*8192;

  if (ws_size >= total_p*sizeof(float)){
    k_zero         <<<2048,          256, 0, stream>>>((float4*)ws, (int)(zero_end>>2));
    k_scatter_all  <<<8*NN*NC/256 + 8*NN/256, 256, 0, stream>>>(
                                                     xsrc, loc, csrc, ws+of_feat,
                                                     ws+of_cnt, ws+of_csum, ws+of_ccnt);
    k_finfillh     <<<8*GH,          256, 0, stream>>>(ws+of_feat, ws+of_cnt, ws+of_feath, ws+of_maskh);
    k_fillv        <<<8*GH,          256, 0, stream>>>(ws+of_feat, ws+of_cnt, ws+of_feath, ws+of_maskh);
    dim3 gconv(32, 8, 2);
    k_srconv2      <<<gconv,         256, 0, stream>>>(ws+of_feat, srw, ws+of_part);
    k_kvfused2     <<<8*GM/4,        256, 0, stream>>>(ws+of_part, srb, nw, nbv, kvw, qw, pw,
                                                       ws+of_csum, ws+of_ccnt, ws+of_conf,
                                                       (ushort*)(ws+of_kb), (ushort*)(ws+of_vb));
    k_attn8        <<<8*NN/16,       64,  0, stream>>>(x, (const ushort*)(ws+of_kb),
                                                       (const ushort*)(ws+of_vb),
                                                       ws+of_conf, pb, out);
  } else {
    // ---------------- fallback: exact round-10 8-batch path ----------------
    size_t f_feat = 0;
    size_t f_cnt  = f_feat + 8ull*GH*GW*NC;
    size_t f_csum = f_cnt  + 8ull*GH*GW;
    size_t f_ccnt = f_csum + 8ull*GM;
    size_t f_xs0  = f_ccnt + 8ull*GM;
    size_t f_zero = f_xs0  + 8ull*GM*NC;
    size_t f_conf = f_zero;
    size_t f_xs   = f_conf + 8ull*GM;
    size_t f_kr   = f_xs   + 8ull*GM*NC;
    size_t f_vr   = f_kr   + 8ull*GM*NC;
    size_t f_kb   = f_vr   + 8ull*GM*NC;
    size_t f_vb   = f_kb   + 8ull*8192;
    hipMemsetAsync(ws, 0, f_zero*sizeof(float), stream);
    k_scatter_feat <<<8*NN*NC/256, 256, 0, stream>>>(xsrc, loc, ws+f_feat);
    k_scatter_aux  <<<8*NN/256,    256, 0, stream>>>(loc, csrc, ws+f_cnt, ws+f_csum, ws+f_ccnt);
    k_finalize_feat<<<8*GH*GW*NC/256, 256, 0, stream>>>(ws+f_feat, ws+f_cnt);
    k_finalize_conf<<<8*GM/256,    256, 0, stream>>>(ws+f_csum, ws+f_ccnt, ws+f_conf);
    k_fill2        <<<8*GH*GW*4/256, 256, 0, stream>>>(ws+f_cnt, ws+f_feat);
    dim3 gconv(8*GM/64, 8);
    k_srconv       <<<gconv,       256, 0, stream>>>(ws+f_feat, srw, ws+f_xs0);
    k_ln           <<<8*GM/4,      256, 0, stream>>>(ws+f_xs0, srb, nw, nbv, ws+f_xs);
    k_kv1          <<<8*GM*NC/256, 256, 0, stream>>>(ws+f_xs, kvw, ws+f_kr, ws+f_vr);
    k_kvproj2      <<<8*GM*NC/256, 256, 0, stream>>>(ws+f_kr, ws+f_vr, qw, pw,
                                                     (ushort*)(ws+f_kb), (ushort*)(ws+f_vb));
    k_attn5        <<<8*NN/64,     256, 0, stream>>>(x, (const ushort*)(ws+f_kb),
                                                     (const ushort*)(ws+f_vb),
                                                     ws+f_conf, pb, out);
  }
}